// Round 1
// baseline (8110.014 us; speedup 1.0000x reference)
//
#include <hip/hip_runtime.h>
#include <hip/hip_bf16.h>
#include <math.h>

// Problem constants
constexpr int Bc   = 8;
constexpr int Sc   = 1024;
constexpr int HIDc = 1024;
constexpr int NHc  = 16;
constexpr int DHc  = 64;
constexpr int Mc   = Bc * Sc;          // 8192 rows for all GEMMs
constexpr float SCALE = 8.0f;          // scores * sqrt(DH); ref divides by DH**-0.5
constexpr float EPS_TERM = 1024.0f * 1e-8f;  // S * ZERO added to the prob-sum

// ---------------------------------------------------------------------------
// Tiled fp32 GEMM: C[m][n] = sum_k A[m][k] * W[n][k] + bias[n]
// mode 0: C row-major [M,N]
// mode 1: C in head layout [B,NH,S,DH]  (m=(b,s), n=(h,d))
// ---------------------------------------------------------------------------
#define GT 64
#define GK 16
__global__ __launch_bounds__(256) void sgemm_bt(
    const float* __restrict__ A, const float* __restrict__ W,
    const float* __restrict__ bias, float* __restrict__ C,
    int M, int N, int K, int mode)
{
  __shared__ float As[GK][GT + 1];
  __shared__ float Bs[GK][GT + 1];

  const int t  = threadIdx.x;
  const int tx = t & 15;         // 0..15 -> n sub-tile
  const int ty = t >> 4;         // 0..15 -> m sub-tile
  const int m0 = blockIdx.y * GT;
  const int n0 = blockIdx.x * GT;

  float acc[4][4] = {};

  const int r  = t >> 2;         // 0..63 row within tile (for staging)
  const int c4 = (t & 3) * 4;    // 0,4,8,12 k-offset (for staging)

  for (int k0 = 0; k0 < K; k0 += GK) {
    float4 av = *(const float4*)(A + (size_t)(m0 + r) * K + k0 + c4);
    float4 wv = *(const float4*)(W + (size_t)(n0 + r) * K + k0 + c4);
    As[c4 + 0][r] = av.x; As[c4 + 1][r] = av.y;
    As[c4 + 2][r] = av.z; As[c4 + 3][r] = av.w;
    Bs[c4 + 0][r] = wv.x; Bs[c4 + 1][r] = wv.y;
    Bs[c4 + 2][r] = wv.z; Bs[c4 + 3][r] = wv.w;
    __syncthreads();

#pragma unroll
    for (int kk = 0; kk < GK; kk++) {
      float a[4], bb[4];
#pragma unroll
      for (int i = 0; i < 4; i++) a[i]  = As[kk][ty * 4 + i];
#pragma unroll
      for (int j = 0; j < 4; j++) bb[j] = Bs[kk][tx * 4 + j];
#pragma unroll
      for (int i = 0; i < 4; i++)
#pragma unroll
        for (int j = 0; j < 4; j++)
          acc[i][j] += a[i] * bb[j];
    }
    __syncthreads();
  }

#pragma unroll
  for (int i = 0; i < 4; i++) {
    const int m = m0 + ty * 4 + i;
#pragma unroll
    for (int j = 0; j < 4; j++) {
      const int n = n0 + tx * 4 + j;
      const float v = acc[i][j] + bias[n];
      if (mode == 0) {
        C[(size_t)m * N + n] = v;
      } else {
        // m = b*S + s ; n = h*DH + d  ->  [B,NH,S,DH]
        const int bb_ = m >> 10, s = m & (Sc - 1);
        const int hh  = n >> 6,  d = n & (DHc - 1);
        C[(((size_t)bb_ * NHc + hh) * Sc + s) * DHc + d] = v;
      }
    }
  }
}

// ---------------------------------------------------------------------------
// Attention: one block (256 thr) per (b, h, q) row.
// scores = q . k * 8 ; softmax over ALL keys ; mask ; renorm by (Zm + S*ZERO*Z)
// ---------------------------------------------------------------------------
__device__ inline float wave_max_f(float v) {
#pragma unroll
  for (int off = 32; off > 0; off >>= 1)
    v = fmaxf(v, __shfl_xor(v, off, 64));
  return v;
}
__device__ inline float wave_sum_f(float v) {
#pragma unroll
  for (int off = 32; off > 0; off >>= 1)
    v += __shfl_xor(v, off, 64);
  return v;
}

__global__ __launch_bounds__(256) void attn_row(
    const float* __restrict__ qh, const float* __restrict__ kh,
    const float* __restrict__ vh, const float* __restrict__ Qm,
    const float* __restrict__ Km, float* __restrict__ ctx)
{
  const int bid = blockIdx.x;          // b*NH*S + h*S + q
  const int q   = bid & (Sc - 1);
  const int bh  = bid >> 10;           // b*NH + h
  const int h   = bh & (NHc - 1);
  const int b   = bh >> 4;

  const float* qrow_g = qh + ((size_t)bh * Sc + q) * DHc;
  const float* Kbase  = kh + (size_t)bh * Sc * DHc;
  const float* Vbase  = vh + (size_t)bh * Sc * DHc;

  __shared__ float qrow[DHc];
  __shared__ float sc[Sc];
  __shared__ float wred[4], wz[4], wzm[4];
  __shared__ float ored[4][DHc];

  const int t  = threadIdx.x;
  const int wv = t >> 6;
  const int ln = t & 63;

  if (t < DHc) qrow[t] = qrow_g[t];
  const float qmask = Qm[b * Sc + q];
  __syncthreads();

  // phase 1: scores
  float lmax = -INFINITY;
  for (int k = t; k < Sc; k += 256) {
    const float4* kr = (const float4*)(Kbase + (size_t)k * DHc);
    float s = 0.0f;
#pragma unroll
    for (int j = 0; j < 16; j++) {
      float4 kv = kr[j];
      s += qrow[4 * j + 0] * kv.x + qrow[4 * j + 1] * kv.y +
           qrow[4 * j + 2] * kv.z + qrow[4 * j + 3] * kv.w;
    }
    s *= SCALE;
    sc[k] = s;
    lmax = fmaxf(lmax, s);
  }
  lmax = wave_max_f(lmax);
  if (ln == 0) wred[wv] = lmax;
  __syncthreads();
  const float bmax = fmaxf(fmaxf(wred[0], wred[1]), fmaxf(wred[2], wred[3]));

  // phase 2: exp, unmasked sum Z, masked sum Zm; sc <- masked exp
  float zl = 0.0f, zml = 0.0f;
  for (int k = t; k < Sc; k += 256) {
    const float p  = __expf(sc[k] - bmax);
    zl += p;
    const float km = Km[b * Sc + k];
    const float pm = (qmask != 0.0f && km != 0.0f) ? p : 0.0f;
    sc[k] = pm;
    zml += pm;
  }
  zl  = wave_sum_f(zl);
  zml = wave_sum_f(zml);
  if (ln == 0) { wz[wv] = zl; wzm[wv] = zml; }
  __syncthreads();
  const float Z    = wz[0] + wz[1] + wz[2] + wz[3];
  const float Zm   = wzm[0] + wzm[1] + wzm[2] + wzm[3];
  const float rden = 1.0f / (Zm + EPS_TERM * Z);

  // phase 3: O[d] = sum_k pm[k] * V[k][d]   (wave wv handles key quarter wv)
  const int d = ln;                      // 0..63
  float o = 0.0f;
  const int kbeg = wv * 256;
  for (int k = kbeg; k < kbeg + 256; k++) {
    o += sc[k] * Vbase[(size_t)k * DHc + d];
  }
  ored[wv][d] = o;
  __syncthreads();
  if (t < DHc) {
    const float of = (ored[0][t] + ored[1][t] + ored[2][t] + ored[3][t]) * rden;
    // ctx layout: [B, S, NH*DH] with hid = h*DH + d
    ctx[((size_t)b * Sc + q) * HIDc + h * DHc + t] = of;
  }
}

// ---------------------------------------------------------------------------
extern "C" void kernel_launch(void* const* d_in, const int* in_sizes, int n_in,
                              void* d_out, int out_size, void* d_ws, size_t ws_size,
                              hipStream_t stream)
{
  const float* Q  = (const float*)d_in[0];
  const float* K  = (const float*)d_in[1];
  const float* V  = (const float*)d_in[2];
  const float* Qm = (const float*)d_in[3];
  const float* Km = (const float*)d_in[4];
  const float* Wq = (const float*)d_in[5];
  const float* bq = (const float*)d_in[6];
  const float* Wk = (const float*)d_in[7];
  const float* bk = (const float*)d_in[8];
  const float* Wv = (const float*)d_in[9];
  const float* bv = (const float*)d_in[10];
  const float* Wo = (const float*)d_in[11];
  const float* bo = (const float*)d_in[12];
  float* out = (float*)d_out;

  const size_t NEL = (size_t)Mc * HIDc;  // 8.39M elements per tensor
  float* qh  = (float*)d_ws;
  float* kh  = qh + NEL;
  float* vh  = kh + NEL;
  float* ctx = vh + NEL;

  dim3 gg(HIDc / GT, Mc / GT);  // (16, 128)
  sgemm_bt<<<gg, 256, 0, stream>>>(Q, Wq, bq, qh, Mc, HIDc, HIDc, 1);
  sgemm_bt<<<gg, 256, 0, stream>>>(K, Wk, bk, kh, Mc, HIDc, HIDc, 1);
  sgemm_bt<<<gg, 256, 0, stream>>>(V, Wv, bv, vh, Mc, HIDc, HIDc, 1);

  attn_row<<<Bc * NHc * Sc, 256, 0, stream>>>(qh, kh, vh, Qm, Km, ctx);

  sgemm_bt<<<gg, 256, 0, stream>>>(ctx, Wo, bo, out, Mc, HIDc, HIDc, 0);
}

// Round 2
// 1600.954 us; speedup vs baseline: 5.0657x; 5.0657x over previous
//
#include <hip/hip_runtime.h>
#include <math.h>

// Problem constants
constexpr int Bc   = 8;
constexpr int Sc   = 1024;
constexpr int HIDc = 1024;
constexpr int NHc  = 16;
constexpr int DHc  = 64;
constexpr int Mc   = Bc * Sc;                 // 8192 rows for all GEMMs
constexpr float SCALE    = 8.0f;              // ref divides by DH**-0.5 == *sqrt(64)
constexpr float EPS_TERM = 1024.0f * 1e-8f;   // S * ZERO in the renorm denominator

typedef short s16x8 __attribute__((ext_vector_type(8)));   // 8 bf16 (4 VGPRs)
typedef float f32x4 __attribute__((ext_vector_type(4)));

__device__ __forceinline__ ushort f2bf(float f) {          // RNE float->bf16 bits
  unsigned u = __float_as_uint(f);
  u += 0x7FFFu + ((u >> 16) & 1u);
  return (ushort)(u >> 16);
}
__device__ __forceinline__ float bf2f(ushort h) {
  return __uint_as_float(((unsigned)h) << 16);
}

// ---------------------------------------------------------------------------
// Tiled fp32 GEMM: C[m][n] = sum_k A[m][k] * W[n][k] + bias[n]
// mode 0: fp32 C row-major [M,N]
// mode 1: bf16 hi/lo pair (C,C2) in head layout [B,NH,S,DH]   (q, k)
// mode 2: bf16 C in transposed head layout [B,NH,DH,S]        (v)
// ---------------------------------------------------------------------------
#define GT 64
#define GK 16
__global__ __launch_bounds__(256) void sgemm_bt(
    const float* __restrict__ A, const float* __restrict__ W,
    const float* __restrict__ bias, void* __restrict__ C, void* __restrict__ C2,
    int M, int N, int K, int mode)
{
  __shared__ float As[GK][GT + 1];
  __shared__ float Bs[GK][GT + 1];

  const int t  = threadIdx.x;
  const int tx = t & 15;
  const int ty = t >> 4;
  const int m0 = blockIdx.y * GT;
  const int n0 = blockIdx.x * GT;

  float acc[4][4] = {};

  const int r  = t >> 2;
  const int c4 = (t & 3) * 4;

  for (int k0 = 0; k0 < K; k0 += GK) {
    float4 av = *(const float4*)(A + (size_t)(m0 + r) * K + k0 + c4);
    float4 wv = *(const float4*)(W + (size_t)(n0 + r) * K + k0 + c4);
    As[c4 + 0][r] = av.x; As[c4 + 1][r] = av.y;
    As[c4 + 2][r] = av.z; As[c4 + 3][r] = av.w;
    Bs[c4 + 0][r] = wv.x; Bs[c4 + 1][r] = wv.y;
    Bs[c4 + 2][r] = wv.z; Bs[c4 + 3][r] = wv.w;
    __syncthreads();

#pragma unroll
    for (int kk = 0; kk < GK; kk++) {
      float a[4], bb[4];
#pragma unroll
      for (int i = 0; i < 4; i++) a[i]  = As[kk][ty * 4 + i];
#pragma unroll
      for (int j = 0; j < 4; j++) bb[j] = Bs[kk][tx * 4 + j];
#pragma unroll
      for (int i = 0; i < 4; i++)
#pragma unroll
        for (int j = 0; j < 4; j++)
          acc[i][j] += a[i] * bb[j];
    }
    __syncthreads();
  }

#pragma unroll
  for (int i = 0; i < 4; i++) {
    const int m = m0 + ty * 4 + i;
#pragma unroll
    for (int j = 0; j < 4; j++) {
      const int n = n0 + tx * 4 + j;
      const float v = acc[i][j] + bias[n];
      if (mode == 0) {
        ((float*)C)[(size_t)m * N + n] = v;
      } else {
        const int bb_ = m >> 10, s = m & (Sc - 1);
        const int hh  = n >> 6,  d = n & (DHc - 1);
        if (mode == 1) {
          const size_t off = (((size_t)bb_ * NHc + hh) * Sc + s) * DHc + d;
          const ushort hb = f2bf(v);
          ((ushort*)C)[off]  = hb;
          ((ushort*)C2)[off] = f2bf(v - bf2f(hb));
        } else {  // mode 2: transposed V
          const size_t off = (((size_t)bb_ * NHc + hh) * DHc + d) * Sc + s;
          ((ushort*)C)[off] = f2bf(v);
        }
      }
    }
  }
}

// ---------------------------------------------------------------------------
// MFMA flash-style attention. Block = (b, h, 64-row q tile); 4 waves, each
// owns 16 q rows. K-loop tiles of 64 keys staged in LDS (shared by waves).
// Scores in near-fp32 via bf16 hi/lo split (3-term MFMA).
// mfma_f32_16x16x32_bf16 layouts (verified m89/m91/m120):
//   A: lane holds A[m=lane&15][k=quad*8+j]
//   B: lane holds B[k=quad*8+j][n=lane&15]
//   C/D: col=lane&15, row=quad*4+reg
// ---------------------------------------------------------------------------
constexpr int TK  = 64;
constexpr int LDK = 72;   // padded LDS row stride (bf16): 144 B, 16B-aligned, 2-way-max banks

__global__ __launch_bounds__(256, 3) void attn_mfma(
    const ushort* __restrict__ qhi, const ushort* __restrict__ qlo,
    const ushort* __restrict__ khi, const ushort* __restrict__ klo,
    const ushort* __restrict__ vt,  const float* __restrict__ Qm,
    const float* __restrict__ Km,   float* __restrict__ ctx)
{
  __shared__ ushort KhiL[64 * LDK];
  __shared__ ushort KloL[64 * LDK];
  __shared__ ushort VtL [64 * LDK];
  __shared__ ushort PmL [64 * LDK];   // 4 waves x 16 rows
  __shared__ float  kmL[TK];

  const int t    = threadIdx.x;
  const int w    = t >> 6;
  const int ln   = t & 63;
  const int col  = ln & 15;
  const int quad = ln >> 4;

  const int blk = blockIdx.x;       // bh*16 + qtile
  const int qt  = blk & 15;
  const int bh  = blk >> 4;
  const int b   = bh >> 4;
  const int h   = bh & 15;

  const int qbase = qt * 64 + w * 16;            // wave's q rows
  const size_t headoff = (size_t)bh * Sc * DHc;  // same for [S,DH] and [DH,S]

  // Q fragments (A-layout), loaded once
  s16x8 qh0, qh1, ql0, ql1;
  {
    const size_t ro = headoff + (size_t)(qbase + col) * DHc + quad * 8;
    qh0 = *(const s16x8*)(qhi + ro);
    qh1 = *(const s16x8*)(qhi + ro + 32);
    ql0 = *(const s16x8*)(qlo + ro);
    ql1 = *(const s16x8*)(qlo + ro + 32);
  }

  f32x4 O[4] = {{0,0,0,0},{0,0,0,0},{0,0,0,0},{0,0,0,0}};
  float mrow[4] = {-INFINITY, -INFINITY, -INFINITY, -INFINITY};
  float Zr[4]   = {0,0,0,0};
  float Zmr[4]  = {0,0,0,0};

  for (int k0 = 0; k0 < Sc; k0 += TK) {
    __syncthreads();  // previous tile fully consumed
    // stage Khi/Klo/Vt tiles (8 KB each) + K-mask
    for (int i = t; i < 512; i += 256) {
      const int rr = i >> 3, cc = (i & 7) * 8;
      *(s16x8*)&KhiL[rr * LDK + cc] = *(const s16x8*)(khi + headoff + (size_t)(k0 + rr) * DHc + cc);
      *(s16x8*)&KloL[rr * LDK + cc] = *(const s16x8*)(klo + headoff + (size_t)(k0 + rr) * DHc + cc);
      *(s16x8*)&VtL [rr * LDK + cc] = *(const s16x8*)(vt  + headoff + (size_t)rr * Sc + k0 + cc);
    }
    if (t < TK) kmL[t] = Km[b * Sc + k0 + t];
    __syncthreads();

    // ---- scores: 4 k-sub-tiles of 16 keys, 3-term hi/lo MFMA ----
    float s[4][4];
#pragma unroll
    for (int ks = 0; ks < 4; ks++) {
      const ushort* kp = &KhiL[(ks * 16 + col) * LDK];
      const ushort* lp = &KloL[(ks * 16 + col) * LDK];
      const s16x8 kh0 = *(const s16x8*)(kp + quad * 8);
      const s16x8 kh1 = *(const s16x8*)(kp + 32 + quad * 8);
      const s16x8 kl0 = *(const s16x8*)(lp + quad * 8);
      const s16x8 kl1 = *(const s16x8*)(lp + 32 + quad * 8);
      f32x4 acc = {0,0,0,0};
      acc = __builtin_amdgcn_mfma_f32_16x16x32_bf16(qh0, kh0, acc, 0, 0, 0);
      acc = __builtin_amdgcn_mfma_f32_16x16x32_bf16(qh1, kh1, acc, 0, 0, 0);
      acc = __builtin_amdgcn_mfma_f32_16x16x32_bf16(qh0, kl0, acc, 0, 0, 0);
      acc = __builtin_amdgcn_mfma_f32_16x16x32_bf16(qh1, kl1, acc, 0, 0, 0);
      acc = __builtin_amdgcn_mfma_f32_16x16x32_bf16(ql0, kh0, acc, 0, 0, 0);
      acc = __builtin_amdgcn_mfma_f32_16x16x32_bf16(ql1, kh1, acc, 0, 0, 0);
#pragma unroll
      for (int r = 0; r < 4; r++) s[ks][r] = acc[r] * SCALE;
    }

    // ---- online softmax update (per-row stats across 16 cols x 4 ksubs) ----
    float kmv[4];
#pragma unroll
    for (int ks = 0; ks < 4; ks++) kmv[ks] = kmL[ks * 16 + col];

    float tmax[4];
#pragma unroll
    for (int r = 0; r < 4; r++)
      tmax[r] = fmaxf(fmaxf(s[0][r], s[1][r]), fmaxf(s[2][r], s[3][r]));
#pragma unroll
    for (int off = 1; off < 16; off <<= 1)
#pragma unroll
      for (int r = 0; r < 4; r++)
        tmax[r] = fmaxf(tmax[r], __shfl_xor(tmax[r], off, 64));

    float alpha[4];
#pragma unroll
    for (int r = 0; r < 4; r++) {
      const float mn = fmaxf(mrow[r], tmax[r]);
      alpha[r] = __expf(mrow[r] - mn);
      mrow[r]  = mn;
    }

    float psum[4] = {0,0,0,0}, pmsum[4] = {0,0,0,0};
#pragma unroll
    for (int ks = 0; ks < 4; ks++)
#pragma unroll
      for (int r = 0; r < 4; r++) {
        const float p  = __expf(s[ks][r] - mrow[r]);
        const float pm = p * kmv[ks];
        psum[r]  += p;
        pmsum[r] += pm;
        s[ks][r]  = pm;
      }
#pragma unroll
    for (int off = 1; off < 16; off <<= 1)
#pragma unroll
      for (int r = 0; r < 4; r++) {
        psum[r]  += __shfl_xor(psum[r],  off, 64);
        pmsum[r] += __shfl_xor(pmsum[r], off, 64);
      }
#pragma unroll
    for (int r = 0; r < 4; r++) {
      Zr[r]  = Zr[r]  * alpha[r] + psum[r];
      Zmr[r] = Zmr[r] * alpha[r] + pmsum[r];
    }

    // write masked P tile (bf16) to this wave's LDS region; rescale O
#pragma unroll
    for (int ks = 0; ks < 4; ks++)
#pragma unroll
      for (int r = 0; r < 4; r++)
        PmL[(w * 16 + quad * 4 + r) * LDK + ks * 16 + col] = f2bf(s[ks][r]);
#pragma unroll
    for (int dt = 0; dt < 4; dt++)
#pragma unroll
      for (int r = 0; r < 4; r++)
        O[dt][r] *= alpha[r];

    // ---- PV: O[16q][64d] += P(16x64) * V(64x64) ----
    const ushort* pp = &PmL[(w * 16 + col) * LDK];
    const s16x8 p0 = *(const s16x8*)(pp + quad * 8);
    const s16x8 p1 = *(const s16x8*)(pp + 32 + quad * 8);
#pragma unroll
    for (int dt = 0; dt < 4; dt++) {
      const ushort* vp = &VtL[(dt * 16 + col) * LDK];
      const s16x8 v0 = *(const s16x8*)(vp + quad * 8);
      const s16x8 v1 = *(const s16x8*)(vp + 32 + quad * 8);
      O[dt] = __builtin_amdgcn_mfma_f32_16x16x32_bf16(p0, v0, O[dt], 0, 0, 0);
      O[dt] = __builtin_amdgcn_mfma_f32_16x16x32_bf16(p1, v1, O[dt], 0, 0, 0);
    }
  }

  // ---- epilogue: renorm + qmask, write ctx [B,S,HID] ----
#pragma unroll
  for (int r = 0; r < 4; r++) {
    const int srow = qbase + quad * 4 + r;
    const float qmv  = Qm[b * Sc + srow];
    const float rden = (qmv != 0.0f) ? 1.0f / (Zmr[r] + EPS_TERM * Zr[r]) : 0.0f;
#pragma unroll
    for (int dt = 0; dt < 4; dt++)
      ctx[((size_t)(b * Sc + srow)) * HIDc + h * DHc + dt * 16 + col] = O[dt][r] * rden;
  }
}

// ---------------------------------------------------------------------------
extern "C" void kernel_launch(void* const* d_in, const int* in_sizes, int n_in,
                              void* d_out, int out_size, void* d_ws, size_t ws_size,
                              hipStream_t stream)
{
  const float* Q  = (const float*)d_in[0];
  const float* K  = (const float*)d_in[1];
  const float* V  = (const float*)d_in[2];
  const float* Qm = (const float*)d_in[3];
  const float* Km = (const float*)d_in[4];
  const float* Wq = (const float*)d_in[5];
  const float* bq = (const float*)d_in[6];
  const float* Wk = (const float*)d_in[7];
  const float* bk = (const float*)d_in[8];
  const float* Wv = (const float*)d_in[9];
  const float* bv = (const float*)d_in[10];
  const float* Wo = (const float*)d_in[11];
  const float* bo = (const float*)d_in[12];
  float* out = (float*)d_out;

  const size_t NEL = (size_t)Mc * HIDc;   // 8.39M
  ushort* qhi = (ushort*)d_ws;
  ushort* qlo = qhi + NEL;
  ushort* khi = qlo + NEL;
  ushort* klo = khi + NEL;
  ushort* vt  = klo + NEL;
  float*  ctx = (float*)(vt + NEL);       // byte offset 10*NEL, 4-aligned

  dim3 gg(HIDc / GT, Mc / GT);            // (16, 128)
  sgemm_bt<<<gg, 256, 0, stream>>>(Q, Wq, bq, qhi, qlo, Mc, HIDc, HIDc, 1);
  sgemm_bt<<<gg, 256, 0, stream>>>(K, Wk, bk, khi, klo, Mc, HIDc, HIDc, 1);
  sgemm_bt<<<gg, 256, 0, stream>>>(V, Wv, bv, vt,  nullptr, Mc, HIDc, HIDc, 2);

  attn_mfma<<<Bc * NHc * (Sc / 64), 256, 0, stream>>>(qhi, qlo, khi, klo, vt, Qm, Km, ctx);

  sgemm_bt<<<gg, 256, 0, stream>>>(ctx, Wo, bo, out, nullptr, Mc, HIDc, HIDc, 0);
}

// Round 3
// 584.760 us; speedup vs baseline: 13.8690x; 2.7378x over previous
//
#include <hip/hip_runtime.h>
#include <math.h>

// Problem constants
constexpr int Bc   = 8;
constexpr int Sc   = 1024;
constexpr int HIDc = 1024;
constexpr int NHc  = 16;
constexpr int DHc  = 64;
constexpr int Mc   = Bc * Sc;                 // 8192 rows for all GEMMs
constexpr int Kc2  = 1024;                    // K dim for all GEMMs
constexpr float SCALE    = 8.0f;              // ref divides by DH**-0.5 == *sqrt(64)
constexpr float EPS_TERM = 1024.0f * 1e-8f;   // S * ZERO in the renorm denominator

typedef short s16x8 __attribute__((ext_vector_type(8)));   // 8 bf16 (4 VGPRs)
typedef float f32x4 __attribute__((ext_vector_type(4)));

__device__ __forceinline__ ushort f2bf(float f) {          // RNE float->bf16 bits
  unsigned u = __float_as_uint(f);
  u += 0x7FFFu + ((u >> 16) & 1u);
  return (ushort)(u >> 16);
}
__device__ __forceinline__ float bf2f(ushort h) {
  return __uint_as_float(((unsigned)h) << 16);
}

// async global->LDS, 16B per lane; LDS dest = wave-uniform base + lane*16
__device__ __forceinline__ void gl_lds16(const ushort* g, ushort* l) {
  __builtin_amdgcn_global_load_lds(
      (const __attribute__((address_space(1))) void*)g,
      (__attribute__((address_space(3))) void*)l, 16, 0, 0);
}

// ---------------------------------------------------------------------------
// fp32 -> bf16 conversions (hi, or hi+lo split)
// ---------------------------------------------------------------------------
__global__ __launch_bounds__(256) void cvt_split(const float4* __restrict__ x,
    ushort4* __restrict__ hi, ushort4* __restrict__ lo, int n4)
{
  const int i = blockIdx.x * 256 + threadIdx.x;
  if (i >= n4) return;
  const float4 v = x[i];
  ushort4 h, l;
  h.x = f2bf(v.x); l.x = f2bf(v.x - bf2f(h.x));
  h.y = f2bf(v.y); l.y = f2bf(v.y - bf2f(h.y));
  h.z = f2bf(v.z); l.z = f2bf(v.z - bf2f(h.z));
  h.w = f2bf(v.w); l.w = f2bf(v.w - bf2f(h.w));
  hi[i] = h; lo[i] = l;
}

__global__ __launch_bounds__(256) void cvt_one(const float4* __restrict__ x,
    ushort4* __restrict__ hi, int n4)
{
  const int i = blockIdx.x * 256 + threadIdx.x;
  if (i >= n4) return;
  const float4 v = x[i];
  ushort4 h;
  h.x = f2bf(v.x); h.y = f2bf(v.y); h.z = f2bf(v.z); h.w = f2bf(v.w);
  hi[i] = h;
}

// ---------------------------------------------------------------------------
// MFMA GEMM: C[m][n] = sum_k A[m][k]*W[n][k] + bias[n]   (A:[M,K], W:[N,K] bf16)
// SPLIT3: A,W given as (hi,lo) bf16 pairs; acc = Ah*Wh + Ah*Wl + Al*Wh  (near-fp32)
// 128x128 block tile, 4 waves in 2x2 of 64x64, BK=32, mfma_f32_16x16x32_bf16.
// LDS chunk-major: chunk s = c*128 + r holds A[m0+r][k0+c*8 .. +8]  (16 B)
//   -> global_load_lds dest is contiguous lane*16; ds_read_b128 frag reads are
//      2-way-max bank aliased (free per m136).
// mode 0: fp32 C row-major [M,N]
// mode 1: bf16 hi/lo pair (C,C2) in head layout [B,NH,S,DH]
// mode 2: bf16 C in transposed head layout [B,NH,DH,S]
// ---------------------------------------------------------------------------
template<bool SPLIT3>
__global__ __launch_bounds__(256, 3) void mfma_gemm(
    const ushort* __restrict__ Ah_g, const ushort* __restrict__ Al_g,
    const ushort* __restrict__ Bh_g, const ushort* __restrict__ Bl_g,
    const float* __restrict__ bias,
    void* __restrict__ C, void* __restrict__ C2, int mode)
{
  __shared__ ushort AhL[4096];
  __shared__ ushort BhL[4096];
  __shared__ ushort AlL[SPLIT3 ? 4096 : 8];
  __shared__ ushort BlL[SPLIT3 ? 4096 : 8];

  const int t    = threadIdx.x;
  const int w    = t >> 6;
  const int ln   = t & 63;
  const int col  = ln & 15;
  const int quad = ln >> 4;
  const int wm   = w >> 1, wn = w & 1;
  const int m0   = blockIdx.y * 128;
  const int n0   = blockIdx.x * 128;

  f32x4 acc[4][4] = {};

  const int sA = w * 128;  // this wave's 128-chunk staging range

  for (int k0 = 0; k0 < Kc2; k0 += 32) {
    __syncthreads();  // previous tile consumed
#pragma unroll
    for (int j = 0; j < 2; j++) {
      const int s = sA + j * 64 + ln;
      const int r = s & 127, c = s >> 7;
      const size_t goA = (size_t)(m0 + r) * Kc2 + k0 + c * 8;
      const size_t goB = (size_t)(n0 + r) * Kc2 + k0 + c * 8;
      ushort* la = &AhL[(size_t)(sA + j * 64) * 8];
      ushort* lb = &BhL[(size_t)(sA + j * 64) * 8];
      gl_lds16(Ah_g + goA, la);
      gl_lds16(Bh_g + goB, lb);
      if constexpr (SPLIT3) {
        gl_lds16(Al_g + goA, &AlL[(size_t)(sA + j * 64) * 8]);
        gl_lds16(Bl_g + goB, &BlL[(size_t)(sA + j * 64) * 8]);
      }
    }
    __syncthreads();  // drains vmcnt

    s16x8 a_h[4], b_h[4], a_l[4], b_l[4];
#pragma unroll
    for (int i = 0; i < 4; i++) {
      const int ai = (quad * 128 + wm * 64 + i * 16 + col) * 8;
      const int bi = (quad * 128 + wn * 64 + i * 16 + col) * 8;
      a_h[i] = *(const s16x8*)&AhL[ai];
      b_h[i] = *(const s16x8*)&BhL[bi];
      if constexpr (SPLIT3) {
        a_l[i] = *(const s16x8*)&AlL[ai];
        b_l[i] = *(const s16x8*)&BlL[bi];
      }
    }
#pragma unroll
    for (int i = 0; i < 4; i++)
#pragma unroll
      for (int jj = 0; jj < 4; jj++) {
        acc[i][jj] = __builtin_amdgcn_mfma_f32_16x16x32_bf16(a_h[i], b_h[jj], acc[i][jj], 0, 0, 0);
        if constexpr (SPLIT3) {
          acc[i][jj] = __builtin_amdgcn_mfma_f32_16x16x32_bf16(a_h[i], b_l[jj], acc[i][jj], 0, 0, 0);
          acc[i][jj] = __builtin_amdgcn_mfma_f32_16x16x32_bf16(a_l[i], b_h[jj], acc[i][jj], 0, 0, 0);
        }
      }
  }

  // epilogue: C/D frag mapping col=lane&15, row=quad*4+reg
  const int mb = m0 + wm * 64;
  const int nb = n0 + wn * 64;
#pragma unroll
  for (int i = 0; i < 4; i++)
#pragma unroll
    for (int jj = 0; jj < 4; jj++) {
      const int n  = nb + jj * 16 + col;
      const float bv = bias[n];
#pragma unroll
      for (int r = 0; r < 4; r++) {
        const int m   = mb + i * 16 + quad * 4 + r;
        const float v = acc[i][jj][r] + bv;
        if (mode == 0) {
          ((float*)C)[(size_t)m * HIDc + n] = v;
        } else {
          const int b_ = m >> 10, s = m & (Sc - 1);
          const int h_ = n >> 6,  d = n & (DHc - 1);
          if (mode == 1) {
            const size_t off = (((size_t)b_ * NHc + h_) * Sc + s) * DHc + d;
            const ushort hb = f2bf(v);
            ((ushort*)C)[off]  = hb;
            ((ushort*)C2)[off] = f2bf(v - bf2f(hb));
          } else {  // mode 2: transposed V
            const size_t off = (((size_t)b_ * NHc + h_) * DHc + d) * Sc + s;
            ((ushort*)C)[off] = f2bf(v);
          }
        }
      }
    }
}

// ---------------------------------------------------------------------------
// MFMA flash-style attention (unchanged from round 2 except bf16 ctx output).
// Block = (b, h, 64-row q tile); 4 waves x 16 q rows; 64-key LDS tiles.
// ---------------------------------------------------------------------------
constexpr int TK  = 64;
constexpr int LDK = 72;   // padded LDS row stride (bf16)

__global__ __launch_bounds__(256, 3) void attn_mfma(
    const ushort* __restrict__ qhi, const ushort* __restrict__ qlo,
    const ushort* __restrict__ khi, const ushort* __restrict__ klo,
    const ushort* __restrict__ vt,  const float* __restrict__ Qm,
    const float* __restrict__ Km,   ushort* __restrict__ ctx)
{
  __shared__ ushort KhiL[64 * LDK];
  __shared__ ushort KloL[64 * LDK];
  __shared__ ushort VtL [64 * LDK];
  __shared__ ushort PmL [64 * LDK];
  __shared__ float  kmL[TK];

  const int t    = threadIdx.x;
  const int w    = t >> 6;
  const int ln   = t & 63;
  const int col  = ln & 15;
  const int quad = ln >> 4;

  const int blk = blockIdx.x;       // bh*16 + qtile
  const int qt  = blk & 15;
  const int bh  = blk >> 4;
  const int b   = bh >> 4;
  const int h   = bh & 15;

  const int qbase = qt * 64 + w * 16;
  const size_t headoff = (size_t)bh * Sc * DHc;

  s16x8 qh0, qh1, ql0, ql1;
  {
    const size_t ro = headoff + (size_t)(qbase + col) * DHc + quad * 8;
    qh0 = *(const s16x8*)(qhi + ro);
    qh1 = *(const s16x8*)(qhi + ro + 32);
    ql0 = *(const s16x8*)(qlo + ro);
    ql1 = *(const s16x8*)(qlo + ro + 32);
  }

  f32x4 O[4] = {{0,0,0,0},{0,0,0,0},{0,0,0,0},{0,0,0,0}};
  float mrow[4] = {-INFINITY, -INFINITY, -INFINITY, -INFINITY};
  float Zr[4]   = {0,0,0,0};
  float Zmr[4]  = {0,0,0,0};

  for (int k0 = 0; k0 < Sc; k0 += TK) {
    __syncthreads();
    for (int i = t; i < 512; i += 256) {
      const int rr = i >> 3, cc = (i & 7) * 8;
      *(s16x8*)&KhiL[rr * LDK + cc] = *(const s16x8*)(khi + headoff + (size_t)(k0 + rr) * DHc + cc);
      *(s16x8*)&KloL[rr * LDK + cc] = *(const s16x8*)(klo + headoff + (size_t)(k0 + rr) * DHc + cc);
      *(s16x8*)&VtL [rr * LDK + cc] = *(const s16x8*)(vt  + headoff + (size_t)rr * Sc + k0 + cc);
    }
    if (t < TK) kmL[t] = Km[b * Sc + k0 + t];
    __syncthreads();

    float s[4][4];
#pragma unroll
    for (int ks = 0; ks < 4; ks++) {
      const ushort* kp = &KhiL[(ks * 16 + col) * LDK];
      const ushort* lp = &KloL[(ks * 16 + col) * LDK];
      const s16x8 kh0 = *(const s16x8*)(kp + quad * 8);
      const s16x8 kh1 = *(const s16x8*)(kp + 32 + quad * 8);
      const s16x8 kl0 = *(const s16x8*)(lp + quad * 8);
      const s16x8 kl1 = *(const s16x8*)(lp + 32 + quad * 8);
      f32x4 acc = {0,0,0,0};
      acc = __builtin_amdgcn_mfma_f32_16x16x32_bf16(qh0, kh0, acc, 0, 0, 0);
      acc = __builtin_amdgcn_mfma_f32_16x16x32_bf16(qh1, kh1, acc, 0, 0, 0);
      acc = __builtin_amdgcn_mfma_f32_16x16x32_bf16(qh0, kl0, acc, 0, 0, 0);
      acc = __builtin_amdgcn_mfma_f32_16x16x32_bf16(qh1, kl1, acc, 0, 0, 0);
      acc = __builtin_amdgcn_mfma_f32_16x16x32_bf16(ql0, kh0, acc, 0, 0, 0);
      acc = __builtin_amdgcn_mfma_f32_16x16x32_bf16(ql1, kh1, acc, 0, 0, 0);
#pragma unroll
      for (int r = 0; r < 4; r++) s[ks][r] = acc[r] * SCALE;
    }

    float kmv[4];
#pragma unroll
    for (int ks = 0; ks < 4; ks++) kmv[ks] = kmL[ks * 16 + col];

    float tmax[4];
#pragma unroll
    for (int r = 0; r < 4; r++)
      tmax[r] = fmaxf(fmaxf(s[0][r], s[1][r]), fmaxf(s[2][r], s[3][r]));
#pragma unroll
    for (int off = 1; off < 16; off <<= 1)
#pragma unroll
      for (int r = 0; r < 4; r++)
        tmax[r] = fmaxf(tmax[r], __shfl_xor(tmax[r], off, 64));

    float alpha[4];
#pragma unroll
    for (int r = 0; r < 4; r++) {
      const float mn = fmaxf(mrow[r], tmax[r]);
      alpha[r] = __expf(mrow[r] - mn);
      mrow[r]  = mn;
    }

    float psum[4] = {0,0,0,0}, pmsum[4] = {0,0,0,0};
#pragma unroll
    for (int ks = 0; ks < 4; ks++)
#pragma unroll
      for (int r = 0; r < 4; r++) {
        const float p  = __expf(s[ks][r] - mrow[r]);
        const float pm = p * kmv[ks];
        psum[r]  += p;
        pmsum[r] += pm;
        s[ks][r]  = pm;
      }
#pragma unroll
    for (int off = 1; off < 16; off <<= 1)
#pragma unroll
      for (int r = 0; r < 4; r++) {
        psum[r]  += __shfl_xor(psum[r],  off, 64);
        pmsum[r] += __shfl_xor(pmsum[r], off, 64);
      }
#pragma unroll
    for (int r = 0; r < 4; r++) {
      Zr[r]  = Zr[r]  * alpha[r] + psum[r];
      Zmr[r] = Zmr[r] * alpha[r] + pmsum[r];
    }

#pragma unroll
    for (int ks = 0; ks < 4; ks++)
#pragma unroll
      for (int r = 0; r < 4; r++)
        PmL[(w * 16 + quad * 4 + r) * LDK + ks * 16 + col] = f2bf(s[ks][r]);
#pragma unroll
    for (int dt = 0; dt < 4; dt++)
#pragma unroll
      for (int r = 0; r < 4; r++)
        O[dt][r] *= alpha[r];

    const ushort* pp = &PmL[(w * 16 + col) * LDK];
    const s16x8 p0 = *(const s16x8*)(pp + quad * 8);
    const s16x8 p1 = *(const s16x8*)(pp + 32 + quad * 8);
#pragma unroll
    for (int dt = 0; dt < 4; dt++) {
      const ushort* vp = &VtL[(dt * 16 + col) * LDK];
      const s16x8 v0 = *(const s16x8*)(vp + quad * 8);
      const s16x8 v1 = *(const s16x8*)(vp + 32 + quad * 8);
      O[dt] = __builtin_amdgcn_mfma_f32_16x16x32_bf16(p0, v0, O[dt], 0, 0, 0);
      O[dt] = __builtin_amdgcn_mfma_f32_16x16x32_bf16(p1, v1, O[dt], 0, 0, 0);
    }
  }

  // epilogue: renorm + qmask, write ctx bf16 [B,S,HID]
#pragma unroll
  for (int r = 0; r < 4; r++) {
    const int srow = qbase + quad * 4 + r;
    const float qmv  = Qm[b * Sc + srow];
    const float rden = (qmv != 0.0f) ? 1.0f / (Zmr[r] + EPS_TERM * Zr[r]) : 0.0f;
#pragma unroll
    for (int dt = 0; dt < 4; dt++)
      ctx[((size_t)(b * Sc + srow)) * HIDc + h * DHc + dt * 16 + col] = f2bf(O[dt][r] * rden);
  }
}

// ---------------------------------------------------------------------------
extern "C" void kernel_launch(void* const* d_in, const int* in_sizes, int n_in,
                              void* d_out, int out_size, void* d_ws, size_t ws_size,
                              hipStream_t stream)
{
  const float* Q  = (const float*)d_in[0];
  const float* K  = (const float*)d_in[1];
  const float* V  = (const float*)d_in[2];
  const float* Qm = (const float*)d_in[3];
  const float* Km = (const float*)d_in[4];
  const float* Wq = (const float*)d_in[5];
  const float* bq = (const float*)d_in[6];
  const float* Wk = (const float*)d_in[7];
  const float* bk = (const float*)d_in[8];
  const float* Wv = (const float*)d_in[9];
  const float* bv = (const float*)d_in[10];
  const float* Wo = (const float*)d_in[11];
  const float* bo = (const float*)d_in[12];
  float* out = (float*)d_out;

  const size_t NEL = (size_t)Mc * HIDc;   // 8.39M
  const size_t WEL = (size_t)HIDc * HIDc; // 1.05M

  ushort* Wqh = (ushort*)d_ws;
  ushort* Wql = Wqh + WEL;
  ushort* Wkh = Wql + WEL;
  ushort* Wkl = Wkh + WEL;
  ushort* Wvh = Wkl + WEL;
  ushort* Woh = Wvh + WEL;
  ushort* qhi = Woh + WEL;
  ushort* qlo = qhi + NEL;
  ushort* khi = qlo + NEL;
  ushort* klo = khi + NEL;
  ushort* vt  = klo + NEL;
  ushort* A0  = vt  + NEL;   // scratch (input conversions), reused
  ushort* A1  = A0  + NEL;   // scratch; later aliased as bf16 ctx
  // total: 6*WEL + 7*NEL ushorts ~= 130 MB

  const int n4i = (int)(NEL / 4);   // 2097152 -> 8192 blocks
  const int n4w = (int)(WEL / 4);   // 262144  -> 1024 blocks

  // weight conversions
  cvt_split<<<n4w / 256, 256, 0, stream>>>((const float4*)Wq, (ushort4*)Wqh, (ushort4*)Wql, n4w);
  cvt_split<<<n4w / 256, 256, 0, stream>>>((const float4*)Wk, (ushort4*)Wkh, (ushort4*)Wkl, n4w);
  cvt_one  <<<n4w / 256, 256, 0, stream>>>((const float4*)Wv, (ushort4*)Wvh, n4w);
  cvt_one  <<<n4w / 256, 256, 0, stream>>>((const float4*)Wo, (ushort4*)Woh, n4w);

  dim3 gg(HIDc / 128, Mc / 128);   // (8, 64)

  // Q projection (3-pass split, near-fp32)
  cvt_split<<<n4i / 256, 256, 0, stream>>>((const float4*)Q, (ushort4*)A0, (ushort4*)A1, n4i);
  mfma_gemm<true><<<gg, 256, 0, stream>>>(A0, A1, Wqh, Wql, bq, qhi, qlo, 1);

  // K projection
  cvt_split<<<n4i / 256, 256, 0, stream>>>((const float4*)K, (ushort4*)A0, (ushort4*)A1, n4i);
  mfma_gemm<true><<<gg, 256, 0, stream>>>(A0, A1, Wkh, Wkl, bk, khi, klo, 1);

  // V projection (single-pass, transposed head layout)
  cvt_one<<<n4i / 256, 256, 0, stream>>>((const float4*)V, (ushort4*)A0, n4i);
  mfma_gemm<false><<<gg, 256, 0, stream>>>(A0, nullptr, Wvh, nullptr, bv, vt, nullptr, 2);

  // attention -> bf16 ctx (reuses A1)
  attn_mfma<<<Bc * NHc * (Sc / 64), 256, 0, stream>>>(qhi, qlo, khi, klo, vt, Qm, Km, A1);

  // output projection
  mfma_gemm<false><<<gg, 256, 0, stream>>>(A1, nullptr, Woh, nullptr, bo, out, nullptr, 0);
}

// Round 4
// 532.424 us; speedup vs baseline: 15.2322x; 1.0983x over previous
//
#include <hip/hip_runtime.h>
#include <math.h>

// Problem constants
constexpr int Bc   = 8;
constexpr int Sc   = 1024;
constexpr int HIDc = 1024;
constexpr int NHc  = 16;
constexpr int DHc  = 64;
constexpr int Mc   = Bc * Sc;                 // 8192 rows for all GEMMs
constexpr int Kc2  = 1024;                    // K dim for all GEMMs
constexpr float SCALE    = 8.0f;              // ref divides by DH**-0.5 == *sqrt(64)
constexpr float EPS_TERM = 1024.0f * 1e-8f;   // S * ZERO in the renorm denominator

typedef short s16x8 __attribute__((ext_vector_type(8)));   // 8 bf16 (4 VGPRs)
typedef float f32x4 __attribute__((ext_vector_type(4)));

__device__ __forceinline__ ushort f2bf(float f) {          // RNE float->bf16 bits
  unsigned u = __float_as_uint(f);
  u += 0x7FFFu + ((u >> 16) & 1u);
  return (ushort)(u >> 16);
}
__device__ __forceinline__ float bf2f(ushort h) {
  return __uint_as_float(((unsigned)h) << 16);
}

// async global->LDS, 16B per lane; LDS dest = wave-uniform base + lane*16
__device__ __forceinline__ void gl_lds16(const ushort* g, ushort* l) {
  __builtin_amdgcn_global_load_lds(
      (const __attribute__((address_space(1))) void*)g,
      (__attribute__((address_space(3))) void*)l, 16, 0, 0);
}

// ---------------------------------------------------------------------------
// fp32 -> bf16 conversions (hi, or hi+lo split)
// ---------------------------------------------------------------------------
__global__ __launch_bounds__(256) void cvt_split(const float4* __restrict__ x,
    ushort4* __restrict__ hi, ushort4* __restrict__ lo, int n4)
{
  const int i = blockIdx.x * 256 + threadIdx.x;
  if (i >= n4) return;
  const float4 v = x[i];
  ushort4 h, l;
  h.x = f2bf(v.x); l.x = f2bf(v.x - bf2f(h.x));
  h.y = f2bf(v.y); l.y = f2bf(v.y - bf2f(h.y));
  h.z = f2bf(v.z); l.z = f2bf(v.z - bf2f(h.z));
  h.w = f2bf(v.w); l.w = f2bf(v.w - bf2f(h.w));
  hi[i] = h; lo[i] = l;
}

__global__ __launch_bounds__(256) void cvt_one(const float4* __restrict__ x,
    ushort4* __restrict__ hi, int n4)
{
  const int i = blockIdx.x * 256 + threadIdx.x;
  if (i >= n4) return;
  const float4 v = x[i];
  ushort4 h;
  h.x = f2bf(v.x); h.y = f2bf(v.y); h.z = f2bf(v.z); h.w = f2bf(v.w);
  hi[i] = h;
}

// all 4 weight conversions in one launch: seg 0=Wq(split) 1=Wk(split) 2=Wv 3=Wo
__global__ __launch_bounds__(256) void cvt_weights(
    const float4* __restrict__ Wq, const float4* __restrict__ Wk,
    const float4* __restrict__ Wv, const float4* __restrict__ Wo,
    ushort4* __restrict__ Wqh, ushort4* __restrict__ Wql,
    ushort4* __restrict__ Wkh, ushort4* __restrict__ Wkl,
    ushort4* __restrict__ Wvh, ushort4* __restrict__ Woh, int n4w)
{
  const int bpseg = n4w / 256;                 // blocks per segment (1024)
  const int seg   = blockIdx.x / bpseg;
  const int li    = (blockIdx.x - seg * bpseg) * 256 + threadIdx.x;
  if (li >= n4w) return;
  if (seg == 0) {
    const float4 v = Wq[li];
    ushort4 h, l;
    h.x = f2bf(v.x); l.x = f2bf(v.x - bf2f(h.x));
    h.y = f2bf(v.y); l.y = f2bf(v.y - bf2f(h.y));
    h.z = f2bf(v.z); l.z = f2bf(v.z - bf2f(h.z));
    h.w = f2bf(v.w); l.w = f2bf(v.w - bf2f(h.w));
    Wqh[li] = h; Wql[li] = l;
  } else if (seg == 1) {
    const float4 v = Wk[li];
    ushort4 h, l;
    h.x = f2bf(v.x); l.x = f2bf(v.x - bf2f(h.x));
    h.y = f2bf(v.y); l.y = f2bf(v.y - bf2f(h.y));
    h.z = f2bf(v.z); l.z = f2bf(v.z - bf2f(h.z));
    h.w = f2bf(v.w); l.w = f2bf(v.w - bf2f(h.w));
    Wkh[li] = h; Wkl[li] = l;
  } else {
    const float4 v = (seg == 2) ? Wv[li] : Wo[li];
    ushort4 h;
    h.x = f2bf(v.x); h.y = f2bf(v.y); h.z = f2bf(v.z); h.w = f2bf(v.w);
    if (seg == 2) Wvh[li] = h; else Woh[li] = h;
  }
}

// ---------------------------------------------------------------------------
// MFMA GEMM: C[m][n] = sum_k A[m][k]*W[n][k] + bias[n]   (A:[M,K], W:[N,K] bf16)
// SPLIT3: A,W given as (hi,lo) bf16 pairs; acc = Ah*Wh + Ah*Wl + Al*Wh  (near-fp32)
// 128x128 block tile, 4 waves in 2x2 of 64x64, BK=32, mfma_f32_16x16x32_bf16.
// mode 0: fp32 C row-major [M,N]
// mode 1: bf16 hi/lo pair (C,C2) in head layout [B,NH,S,DH]
// mode 2: bf16 C in transposed head layout [B,NH,DH,S]
// ---------------------------------------------------------------------------
template<bool SPLIT3>
__global__ __launch_bounds__(256, 3) void mfma_gemm(
    const ushort* __restrict__ Ah_g, const ushort* __restrict__ Al_g,
    const ushort* __restrict__ Bh_g, const ushort* __restrict__ Bl_g,
    const float* __restrict__ bias,
    void* __restrict__ C, void* __restrict__ C2, int mode)
{
  __shared__ ushort AhL[4096];
  __shared__ ushort BhL[4096];
  __shared__ ushort AlL[SPLIT3 ? 4096 : 8];
  __shared__ ushort BlL[SPLIT3 ? 4096 : 8];

  const int t    = threadIdx.x;
  const int w    = t >> 6;
  const int ln   = t & 63;
  const int col  = ln & 15;
  const int quad = ln >> 4;
  const int wm   = w >> 1, wn = w & 1;
  const int m0   = blockIdx.y * 128;
  const int n0   = blockIdx.x * 128;

  f32x4 acc[4][4] = {};

  const int sA = w * 128;  // this wave's 128-chunk staging range

  for (int k0 = 0; k0 < Kc2; k0 += 32) {
    __syncthreads();  // previous tile consumed
#pragma unroll
    for (int j = 0; j < 2; j++) {
      const int s = sA + j * 64 + ln;
      const int r = s & 127, c = s >> 7;
      const size_t goA = (size_t)(m0 + r) * Kc2 + k0 + c * 8;
      const size_t goB = (size_t)(n0 + r) * Kc2 + k0 + c * 8;
      ushort* la = &AhL[(size_t)(sA + j * 64) * 8];
      ushort* lb = &BhL[(size_t)(sA + j * 64) * 8];
      gl_lds16(Ah_g + goA, la);
      gl_lds16(Bh_g + goB, lb);
      if constexpr (SPLIT3) {
        gl_lds16(Al_g + goA, &AlL[(size_t)(sA + j * 64) * 8]);
        gl_lds16(Bl_g + goB, &BlL[(size_t)(sA + j * 64) * 8]);
      }
    }
    __syncthreads();  // drains vmcnt

    s16x8 a_h[4], b_h[4], a_l[4], b_l[4];
#pragma unroll
    for (int i = 0; i < 4; i++) {
      const int ai = (quad * 128 + wm * 64 + i * 16 + col) * 8;
      const int bi = (quad * 128 + wn * 64 + i * 16 + col) * 8;
      a_h[i] = *(const s16x8*)&AhL[ai];
      b_h[i] = *(const s16x8*)&BhL[bi];
      if constexpr (SPLIT3) {
        a_l[i] = *(const s16x8*)&AlL[ai];
        b_l[i] = *(const s16x8*)&BlL[bi];
      }
    }
#pragma unroll
    for (int i = 0; i < 4; i++)
#pragma unroll
      for (int jj = 0; jj < 4; jj++) {
        acc[i][jj] = __builtin_amdgcn_mfma_f32_16x16x32_bf16(a_h[i], b_h[jj], acc[i][jj], 0, 0, 0);
        if constexpr (SPLIT3) {
          acc[i][jj] = __builtin_amdgcn_mfma_f32_16x16x32_bf16(a_h[i], b_l[jj], acc[i][jj], 0, 0, 0);
          acc[i][jj] = __builtin_amdgcn_mfma_f32_16x16x32_bf16(a_l[i], b_h[jj], acc[i][jj], 0, 0, 0);
        }
      }
  }

  // epilogue: C/D frag mapping col=lane&15, row=quad*4+reg
  const int mb = m0 + wm * 64;
  const int nb = n0 + wn * 64;
#pragma unroll
  for (int i = 0; i < 4; i++)
#pragma unroll
    for (int jj = 0; jj < 4; jj++) {
      const int n  = nb + jj * 16 + col;
      const float bv = bias[n];
#pragma unroll
      for (int r = 0; r < 4; r++) {
        const int m   = mb + i * 16 + quad * 4 + r;
        const float v = acc[i][jj][r] + bv;
        if (mode == 0) {
          ((float*)C)[(size_t)m * HIDc + n] = v;
        } else {
          const int b_ = m >> 10, s = m & (Sc - 1);
          const int h_ = n >> 6,  d = n & (DHc - 1);
          if (mode == 1) {
            const size_t off = (((size_t)b_ * NHc + h_) * Sc + s) * DHc + d;
            const ushort hb = f2bf(v);
            ((ushort*)C)[off]  = hb;
            ((ushort*)C2)[off] = f2bf(v - bf2f(hb));
          } else {  // mode 2: transposed V
            const size_t off = (((size_t)b_ * NHc + h_) * DHc + d) * Sc + s;
            ((ushort*)C)[off] = f2bf(v);
          }
        }
      }
    }
}

// ---------------------------------------------------------------------------
// MFMA flash-style attention.
// Block = (b, h, 64-row q tile); 4 waves x 16 q rows; 64-key LDS tiles.
// R4: XCD-aware block remap (16 q-tiles of a head share an XCD);
//     LDK=80 for K/V (uniform-bank b128 frag reads), P tile at stride 72;
//     Z/Zm kept as per-lane partials, reduced once in the epilogue.
// ---------------------------------------------------------------------------
constexpr int TK  = 64;
constexpr int LDK = 80;   // K/V LDS row stride (bf16): bank start 8*(col&3)+4*quad -> uniform
constexpr int LDP = 72;   // P LDS row stride

__global__ __launch_bounds__(256, 3) void attn_mfma(
    const ushort* __restrict__ qhi, const ushort* __restrict__ qlo,
    const ushort* __restrict__ khi, const ushort* __restrict__ klo,
    const ushort* __restrict__ vt,  const float* __restrict__ Qm,
    const float* __restrict__ Km,   ushort* __restrict__ ctx)
{
  __shared__ ushort KhiL[64 * LDK];
  __shared__ ushort KloL[64 * LDK];
  __shared__ ushort VtL [64 * LDK];
  __shared__ ushort PmL [64 * LDP];
  __shared__ float  kmL[TK];

  const int t    = threadIdx.x;
  const int w    = t >> 6;
  const int ln   = t & 63;
  const int col  = ln & 15;
  const int quad = ln >> 4;

  // XCD-aware remap: round-robin dispatch puts blk%8 on XCD blk&7.
  // Give each XCD 16 whole heads, q-tiles of a head consecutive on that XCD.
  const int id  = blockIdx.x;          // 0..2047
  const int xcd = id & 7;
  const int j   = id >> 3;             // 0..255
  const int bh  = xcd * 16 + (j >> 4); // head group per XCD
  const int qt  = j & 15;
  const int b   = bh >> 4;
  const int h   = bh & 15;

  const int qbase = qt * 64 + w * 16;
  const size_t headoff = (size_t)bh * Sc * DHc;

  s16x8 qh0, qh1, ql0, ql1;
  {
    const size_t ro = headoff + (size_t)(qbase + col) * DHc + quad * 8;
    qh0 = *(const s16x8*)(qhi + ro);
    qh1 = *(const s16x8*)(qhi + ro + 32);
    ql0 = *(const s16x8*)(qlo + ro);
    ql1 = *(const s16x8*)(qlo + ro + 32);
  }

  f32x4 O[4] = {{0,0,0,0},{0,0,0,0},{0,0,0,0},{0,0,0,0}};
  float mrow[4] = {-INFINITY, -INFINITY, -INFINITY, -INFINITY};
  float Zr[4]   = {0,0,0,0};   // per-lane partials (own 4 columns); reduced in epilogue
  float Zmr[4]  = {0,0,0,0};

  for (int k0 = 0; k0 < Sc; k0 += TK) {
    __syncthreads();
    for (int i = t; i < 512; i += 256) {
      const int rr = i >> 3, cc = (i & 7) * 8;
      *(s16x8*)&KhiL[rr * LDK + cc] = *(const s16x8*)(khi + headoff + (size_t)(k0 + rr) * DHc + cc);
      *(s16x8*)&KloL[rr * LDK + cc] = *(const s16x8*)(klo + headoff + (size_t)(k0 + rr) * DHc + cc);
      *(s16x8*)&VtL [rr * LDK + cc] = *(const s16x8*)(vt  + headoff + (size_t)rr * Sc + k0 + cc);
    }
    if (t < TK) kmL[t] = Km[b * Sc + k0 + t];
    __syncthreads();

    float s[4][4];
#pragma unroll
    for (int ks = 0; ks < 4; ks++) {
      const ushort* kp = &KhiL[(ks * 16 + col) * LDK];
      const ushort* lp = &KloL[(ks * 16 + col) * LDK];
      const s16x8 kh0 = *(const s16x8*)(kp + quad * 8);
      const s16x8 kh1 = *(const s16x8*)(kp + 32 + quad * 8);
      const s16x8 kl0 = *(const s16x8*)(lp + quad * 8);
      const s16x8 kl1 = *(const s16x8*)(lp + 32 + quad * 8);
      f32x4 acc = {0,0,0,0};
      acc = __builtin_amdgcn_mfma_f32_16x16x32_bf16(qh0, kh0, acc, 0, 0, 0);
      acc = __builtin_amdgcn_mfma_f32_16x16x32_bf16(qh1, kh1, acc, 0, 0, 0);
      acc = __builtin_amdgcn_mfma_f32_16x16x32_bf16(qh0, kl0, acc, 0, 0, 0);
      acc = __builtin_amdgcn_mfma_f32_16x16x32_bf16(qh1, kl1, acc, 0, 0, 0);
      acc = __builtin_amdgcn_mfma_f32_16x16x32_bf16(ql0, kh0, acc, 0, 0, 0);
      acc = __builtin_amdgcn_mfma_f32_16x16x32_bf16(ql1, kh1, acc, 0, 0, 0);
#pragma unroll
      for (int r = 0; r < 4; r++) s[ks][r] = acc[r] * SCALE;
    }

    float kmv[4];
#pragma unroll
    for (int ks = 0; ks < 4; ks++) kmv[ks] = kmL[ks * 16 + col];

    // row max (cross-lane within quad -> uniform per q-row)
    float tmax[4];
#pragma unroll
    for (int r = 0; r < 4; r++)
      tmax[r] = fmaxf(fmaxf(s[0][r], s[1][r]), fmaxf(s[2][r], s[3][r]));
#pragma unroll
    for (int off = 1; off < 16; off <<= 1)
#pragma unroll
      for (int r = 0; r < 4; r++)
        tmax[r] = fmaxf(tmax[r], __shfl_xor(tmax[r], off, 64));

    float alpha[4];
#pragma unroll
    for (int r = 0; r < 4; r++) {
      const float mn = fmaxf(mrow[r], tmax[r]);
      alpha[r] = __expf(mrow[r] - mn);
      mrow[r]  = mn;
    }

    // per-lane partial sums only (no per-tile cross-lane reduction)
#pragma unroll
    for (int r = 0; r < 4; r++) {
      float ps = 0.0f, pms = 0.0f;
#pragma unroll
      for (int ks = 0; ks < 4; ks++) {
        const float p  = __expf(s[ks][r] - mrow[r]);
        const float pm = p * kmv[ks];
        ps  += p;
        pms += pm;
        s[ks][r] = pm;
      }
      Zr[r]  = Zr[r]  * alpha[r] + ps;
      Zmr[r] = Zmr[r] * alpha[r] + pms;
    }

#pragma unroll
    for (int ks = 0; ks < 4; ks++)
#pragma unroll
      for (int r = 0; r < 4; r++)
        PmL[(w * 16 + quad * 4 + r) * LDP + ks * 16 + col] = f2bf(s[ks][r]);
#pragma unroll
    for (int dt = 0; dt < 4; dt++)
#pragma unroll
      for (int r = 0; r < 4; r++)
        O[dt][r] *= alpha[r];

    const ushort* pp = &PmL[(w * 16 + col) * LDP];
    const s16x8 p0 = *(const s16x8*)(pp + quad * 8);
    const s16x8 p1 = *(const s16x8*)(pp + 32 + quad * 8);
#pragma unroll
    for (int dt = 0; dt < 4; dt++) {
      const ushort* vp = &VtL[(dt * 16 + col) * LDK];
      const s16x8 v0 = *(const s16x8*)(vp + quad * 8);
      const s16x8 v1 = *(const s16x8*)(vp + 32 + quad * 8);
      O[dt] = __builtin_amdgcn_mfma_f32_16x16x32_bf16(p0, v0, O[dt], 0, 0, 0);
      O[dt] = __builtin_amdgcn_mfma_f32_16x16x32_bf16(p1, v1, O[dt], 0, 0, 0);
    }
  }

  // deferred Z/Zm reduction (once)
#pragma unroll
  for (int off = 1; off < 16; off <<= 1)
#pragma unroll
    for (int r = 0; r < 4; r++) {
      Zr[r]  += __shfl_xor(Zr[r],  off, 64);
      Zmr[r] += __shfl_xor(Zmr[r], off, 64);
    }

  // epilogue: renorm + qmask, write ctx bf16 [B,S,HID]
#pragma unroll
  for (int r = 0; r < 4; r++) {
    const int srow = qbase + quad * 4 + r;
    const float qmv  = Qm[b * Sc + srow];
    const float rden = (qmv != 0.0f) ? 1.0f / (Zmr[r] + EPS_TERM * Zr[r]) : 0.0f;
#pragma unroll
    for (int dt = 0; dt < 4; dt++)
      ctx[((size_t)(b * Sc + srow)) * HIDc + h * DHc + dt * 16 + col] = f2bf(O[dt][r] * rden);
  }
}

// ---------------------------------------------------------------------------
extern "C" void kernel_launch(void* const* d_in, const int* in_sizes, int n_in,
                              void* d_out, int out_size, void* d_ws, size_t ws_size,
                              hipStream_t stream)
{
  const float* Q  = (const float*)d_in[0];
  const float* K  = (const float*)d_in[1];
  const float* V  = (const float*)d_in[2];
  const float* Qm = (const float*)d_in[3];
  const float* Km = (const float*)d_in[4];
  const float* Wq = (const float*)d_in[5];
  const float* bq = (const float*)d_in[6];
  const float* Wk = (const float*)d_in[7];
  const float* bk = (const float*)d_in[8];
  const float* Wv = (const float*)d_in[9];
  const float* bv = (const float*)d_in[10];
  const float* Wo = (const float*)d_in[11];
  const float* bo = (const float*)d_in[12];
  float* out = (float*)d_out;

  const size_t NEL = (size_t)Mc * HIDc;   // 8.39M
  const size_t WEL = (size_t)HIDc * HIDc; // 1.05M

  ushort* Wqh = (ushort*)d_ws;
  ushort* Wql = Wqh + WEL;
  ushort* Wkh = Wql + WEL;
  ushort* Wkl = Wkh + WEL;
  ushort* Wvh = Wkl + WEL;
  ushort* Woh = Wvh + WEL;
  ushort* qhi = Woh + WEL;
  ushort* qlo = qhi + NEL;
  ushort* khi = qlo + NEL;
  ushort* klo = khi + NEL;
  ushort* vt  = klo + NEL;
  ushort* A0  = vt  + NEL;   // scratch (input conversions), reused
  ushort* A1  = A0  + NEL;   // scratch; later aliased as bf16 ctx
  // total: 6*WEL + 7*NEL ushorts ~= 130 MB

  const int n4i = (int)(NEL / 4);   // 2097152 -> 8192 blocks
  const int n4w = (int)(WEL / 4);   // 262144  -> 1024 blocks/segment

  // all weight conversions in one launch
  cvt_weights<<<4 * (n4w / 256), 256, 0, stream>>>(
      (const float4*)Wq, (const float4*)Wk, (const float4*)Wv, (const float4*)Wo,
      (ushort4*)Wqh, (ushort4*)Wql, (ushort4*)Wkh, (ushort4*)Wkl,
      (ushort4*)Wvh, (ushort4*)Woh, n4w);

  dim3 gg(HIDc / 128, Mc / 128);   // (8, 64)

  // Q projection (3-pass split, near-fp32)
  cvt_split<<<n4i / 256, 256, 0, stream>>>((const float4*)Q, (ushort4*)A0, (ushort4*)A1, n4i);
  mfma_gemm<true><<<gg, 256, 0, stream>>>(A0, A1, Wqh, Wql, bq, qhi, qlo, 1);

  // K projection
  cvt_split<<<n4i / 256, 256, 0, stream>>>((const float4*)K, (ushort4*)A0, (ushort4*)A1, n4i);
  mfma_gemm<true><<<gg, 256, 0, stream>>>(A0, A1, Wkh, Wkl, bk, khi, klo, 1);

  // V projection (single-pass, transposed head layout)
  cvt_one<<<n4i / 256, 256, 0, stream>>>((const float4*)V, (ushort4*)A0, n4i);
  mfma_gemm<false><<<gg, 256, 0, stream>>>(A0, nullptr, Wvh, nullptr, bv, vt, nullptr, 2);

  // attention -> bf16 ctx (reuses A1)
  attn_mfma<<<Bc * NHc * (Sc / 64), 256, 0, stream>>>(qhi, qlo, khi, klo, vt, Qm, Km, A1);

  // output projection
  mfma_gemm<false><<<gg, 256, 0, stream>>>(A1, nullptr, Woh, nullptr, bo, out, nullptr, 0);
}

// Round 5
// 531.488 us; speedup vs baseline: 15.2591x; 1.0018x over previous
//
#include <hip/hip_runtime.h>
#include <math.h>

// Problem constants
constexpr int Bc   = 8;
constexpr int Sc   = 1024;
constexpr int HIDc = 1024;
constexpr int NHc  = 16;
constexpr int DHc  = 64;
constexpr int Mc   = Bc * Sc;                 // 8192 rows for all GEMMs
constexpr int Kc2  = 1024;                    // K dim for all GEMMs
constexpr float SCALE    = 8.0f;              // ref divides by DH**-0.5 == *sqrt(64)
constexpr float EPS_TERM = 1024.0f * 1e-8f;   // S * ZERO in the renorm denominator

typedef short s16x8 __attribute__((ext_vector_type(8)));   // 8 bf16 (4 VGPRs)
typedef float f32x4 __attribute__((ext_vector_type(4)));

__device__ __forceinline__ ushort f2bf(float f) {          // RNE float->bf16 bits
  unsigned u = __float_as_uint(f);
  u += 0x7FFFu + ((u >> 16) & 1u);
  return (ushort)(u >> 16);
}
__device__ __forceinline__ float bf2f(ushort h) {
  return __uint_as_float(((unsigned)h) << 16);
}
__device__ __forceinline__ unsigned pk2bf(float a, float b) {  // pack 2 bf16
  return (unsigned)f2bf(a) | ((unsigned)f2bf(b) << 16);
}

// async global->LDS, 16B per lane; LDS dest = wave-uniform base + lane*16
__device__ __forceinline__ void gl_lds16(const ushort* g, ushort* l) {
  __builtin_amdgcn_global_load_lds(
      (const __attribute__((address_space(1))) void*)g,
      (__attribute__((address_space(3))) void*)l, 16, 0, 0);
}

// ---------------------------------------------------------------------------
// fp32 -> bf16 conversions (hi, or hi+lo split)
// ---------------------------------------------------------------------------
__global__ __launch_bounds__(256) void cvt_split(const float4* __restrict__ x,
    ushort4* __restrict__ hi, ushort4* __restrict__ lo, int n4)
{
  const int i = blockIdx.x * 256 + threadIdx.x;
  if (i >= n4) return;
  const float4 v = x[i];
  ushort4 h, l;
  h.x = f2bf(v.x); l.x = f2bf(v.x - bf2f(h.x));
  h.y = f2bf(v.y); l.y = f2bf(v.y - bf2f(h.y));
  h.z = f2bf(v.z); l.z = f2bf(v.z - bf2f(h.z));
  h.w = f2bf(v.w); l.w = f2bf(v.w - bf2f(h.w));
  hi[i] = h; lo[i] = l;
}

__global__ __launch_bounds__(256) void cvt_one(const float4* __restrict__ x,
    ushort4* __restrict__ hi, int n4)
{
  const int i = blockIdx.x * 256 + threadIdx.x;
  if (i >= n4) return;
  const float4 v = x[i];
  ushort4 h;
  h.x = f2bf(v.x); h.y = f2bf(v.y); h.z = f2bf(v.z); h.w = f2bf(v.w);
  hi[i] = h;
}

// all 4 weight conversions in one launch: seg 0=Wq(split) 1=Wk(split) 2=Wv 3=Wo
__global__ __launch_bounds__(256) void cvt_weights(
    const float4* __restrict__ Wq, const float4* __restrict__ Wk,
    const float4* __restrict__ Wv, const float4* __restrict__ Wo,
    ushort4* __restrict__ Wqh, ushort4* __restrict__ Wql,
    ushort4* __restrict__ Wkh, ushort4* __restrict__ Wkl,
    ushort4* __restrict__ Wvh, ushort4* __restrict__ Woh, int n4w)
{
  const int bpseg = n4w / 256;                 // blocks per segment (1024)
  const int seg   = blockIdx.x / bpseg;
  const int li    = (blockIdx.x - seg * bpseg) * 256 + threadIdx.x;
  if (li >= n4w) return;
  if (seg == 0) {
    const float4 v = Wq[li];
    ushort4 h, l;
    h.x = f2bf(v.x); l.x = f2bf(v.x - bf2f(h.x));
    h.y = f2bf(v.y); l.y = f2bf(v.y - bf2f(h.y));
    h.z = f2bf(v.z); l.z = f2bf(v.z - bf2f(h.z));
    h.w = f2bf(v.w); l.w = f2bf(v.w - bf2f(h.w));
    Wqh[li] = h; Wql[li] = l;
  } else if (seg == 1) {
    const float4 v = Wk[li];
    ushort4 h, l;
    h.x = f2bf(v.x); l.x = f2bf(v.x - bf2f(h.x));
    h.y = f2bf(v.y); l.y = f2bf(v.y - bf2f(h.y));
    h.z = f2bf(v.z); l.z = f2bf(v.z - bf2f(h.z));
    h.w = f2bf(v.w); l.w = f2bf(v.w - bf2f(h.w));
    Wkh[li] = h; Wkl[li] = l;
  } else {
    const float4 v = (seg == 2) ? Wv[li] : Wo[li];
    ushort4 h;
    h.x = f2bf(v.x); h.y = f2bf(v.y); h.z = f2bf(v.z); h.w = f2bf(v.w);
    if (seg == 2) Wvh[li] = h; else Woh[li] = h;
  }
}

// ---------------------------------------------------------------------------
// MFMA GEMM: C[m][n] = sum_k A[m][k]*W[n][k] + bias[n]   (A:[M,K], W:[N,K] bf16)
// SPLIT3: A,W given as (hi,lo) bf16 pairs; acc = Ah*Wh + Ah*Wl + Al*Wh  (near-fp32)
// 128x128 block tile, 4 waves in 2x2 of 64x64, BK=32, mfma_f32_16x16x32_bf16.
// mode 0: fp32 C row-major [M,N]
// mode 1: bf16 hi/lo pair (C,C2) in head layout [B,NH,S,DH]
// mode 2: bf16 C in transposed head layout [B,NH,DH,S]
// ---------------------------------------------------------------------------
template<bool SPLIT3>
__global__ __launch_bounds__(256, 3) void mfma_gemm(
    const ushort* __restrict__ Ah_g, const ushort* __restrict__ Al_g,
    const ushort* __restrict__ Bh_g, const ushort* __restrict__ Bl_g,
    const float* __restrict__ bias,
    void* __restrict__ C, void* __restrict__ C2, int mode)
{
  __shared__ ushort AhL[4096];
  __shared__ ushort BhL[4096];
  __shared__ ushort AlL[SPLIT3 ? 4096 : 8];
  __shared__ ushort BlL[SPLIT3 ? 4096 : 8];

  const int t    = threadIdx.x;
  const int w    = t >> 6;
  const int ln   = t & 63;
  const int col  = ln & 15;
  const int quad = ln >> 4;
  const int wm   = w >> 1, wn = w & 1;
  const int m0   = blockIdx.y * 128;
  const int n0   = blockIdx.x * 128;

  f32x4 acc[4][4] = {};

  const int sA = w * 128;  // this wave's 128-chunk staging range

  for (int k0 = 0; k0 < Kc2; k0 += 32) {
    __syncthreads();  // previous tile consumed
#pragma unroll
    for (int j = 0; j < 2; j++) {
      const int s = sA + j * 64 + ln;
      const int r = s & 127, c = s >> 7;
      const size_t goA = (size_t)(m0 + r) * Kc2 + k0 + c * 8;
      const size_t goB = (size_t)(n0 + r) * Kc2 + k0 + c * 8;
      ushort* la = &AhL[(size_t)(sA + j * 64) * 8];
      ushort* lb = &BhL[(size_t)(sA + j * 64) * 8];
      gl_lds16(Ah_g + goA, la);
      gl_lds16(Bh_g + goB, lb);
      if constexpr (SPLIT3) {
        gl_lds16(Al_g + goA, &AlL[(size_t)(sA + j * 64) * 8]);
        gl_lds16(Bl_g + goB, &BlL[(size_t)(sA + j * 64) * 8]);
      }
    }
    __syncthreads();  // drains vmcnt

    s16x8 a_h[4], b_h[4], a_l[4], b_l[4];
#pragma unroll
    for (int i = 0; i < 4; i++) {
      const int ai = (quad * 128 + wm * 64 + i * 16 + col) * 8;
      const int bi = (quad * 128 + wn * 64 + i * 16 + col) * 8;
      a_h[i] = *(const s16x8*)&AhL[ai];
      b_h[i] = *(const s16x8*)&BhL[bi];
      if constexpr (SPLIT3) {
        a_l[i] = *(const s16x8*)&AlL[ai];
        b_l[i] = *(const s16x8*)&BlL[bi];
      }
    }
#pragma unroll
    for (int i = 0; i < 4; i++)
#pragma unroll
      for (int jj = 0; jj < 4; jj++) {
        acc[i][jj] = __builtin_amdgcn_mfma_f32_16x16x32_bf16(a_h[i], b_h[jj], acc[i][jj], 0, 0, 0);
        if constexpr (SPLIT3) {
          acc[i][jj] = __builtin_amdgcn_mfma_f32_16x16x32_bf16(a_h[i], b_l[jj], acc[i][jj], 0, 0, 0);
          acc[i][jj] = __builtin_amdgcn_mfma_f32_16x16x32_bf16(a_l[i], b_h[jj], acc[i][jj], 0, 0, 0);
        }
      }
  }

  // epilogue: C/D frag mapping col=lane&15, row=quad*4+reg
  const int mb = m0 + wm * 64;
  const int nb = n0 + wn * 64;
#pragma unroll
  for (int i = 0; i < 4; i++)
#pragma unroll
    for (int jj = 0; jj < 4; jj++) {
      const int n  = nb + jj * 16 + col;
      const float bv = bias[n];
#pragma unroll
      for (int r = 0; r < 4; r++) {
        const int m   = mb + i * 16 + quad * 4 + r;
        const float v = acc[i][jj][r] + bv;
        if (mode == 0) {
          ((float*)C)[(size_t)m * HIDc + n] = v;
        } else {
          const int b_ = m >> 10, s = m & (Sc - 1);
          const int h_ = n >> 6,  d = n & (DHc - 1);
          if (mode == 1) {
            const size_t off = (((size_t)b_ * NHc + h_) * Sc + s) * DHc + d;
            const ushort hb = f2bf(v);
            ((ushort*)C)[off]  = hb;
            ((ushort*)C2)[off] = f2bf(v - bf2f(hb));
          } else {  // mode 2: transposed V
            const size_t off = (((size_t)b_ * NHc + h_) * DHc + d) * Sc + s;
            ((ushort*)C)[off] = f2bf(v);
          }
        }
      }
    }
}

// ---------------------------------------------------------------------------
// MFMA flash attention, S^T orientation (R5).
// Block = (b, h, 64-q tile); 4 waves x 16 q rows; 64-key LDS tiles.
//   S^T = K·Q^T  (swap MFMA args; C-layout: lane holds S[q=col][k=ks*16+quad*4+r])
//   -> softmax stats lane-local over k; alpha is 1 exp/lane; P written as
//      packed b64 into [q][k] LDS; O^T = V^T·P^T (A=V^T contiguous, B=P^T b128).
// K/V staged chunk-major (unpadded) via global_load_lds width=16:
//   chunk c*64+r holds row r, k-chunk c (16B); frag reads bank-uniform.
// ---------------------------------------------------------------------------
constexpr int LDP = 72;   // P LDS row stride (ushorts); keeps b64/b128 bank-uniform

__global__ __launch_bounds__(256, 4) void attn_mfma(
    const ushort* __restrict__ qhi, const ushort* __restrict__ qlo,
    const ushort* __restrict__ khi, const ushort* __restrict__ klo,
    const ushort* __restrict__ vt,  const float* __restrict__ Qm,
    const float* __restrict__ Km,   ushort* __restrict__ ctx)
{
  __shared__ ushort KhiL[4096];     // 512 chunks x 16B, chunk c*64+r = Khi[r][c*8..+8]
  __shared__ ushort KloL[4096];
  __shared__ ushort VtL [4096];     // chunk c*64+d = V^T[d][c*8..+8]
  __shared__ ushort PmL [64 * LDP]; // [q_local][k], per-wave 16 rows
  __shared__ float  kmL[64];

  const int t    = threadIdx.x;
  const int w    = t >> 6;
  const int ln   = t & 63;
  const int col  = ln & 15;
  const int quad = ln >> 4;

  // XCD-aware remap: 16 whole heads per XCD, q-tiles of a head on one XCD.
  const int id  = blockIdx.x;          // 0..2047
  const int xcd = id & 7;
  const int j   = id >> 3;             // 0..255
  const int bh  = xcd * 16 + (j >> 4);
  const int qt  = j & 15;
  const int b   = bh >> 4;
  const int h   = bh & 15;

  const int qbase = qt * 64 + w * 16;
  const size_t headoff = (size_t)bh * Sc * DHc;

  // Q fragments (B-operand of S^T = K·Q^T): lane holds Q[qbase+col][quad*8+j]
  s16x8 qh0, qh1, ql0, ql1;
  {
    const size_t ro = headoff + (size_t)(qbase + col) * DHc + quad * 8;
    qh0 = *(const s16x8*)(qhi + ro);
    qh1 = *(const s16x8*)(qhi + ro + 32);
    ql0 = *(const s16x8*)(qlo + ro);
    ql1 = *(const s16x8*)(qlo + ro + 32);
  }

  f32x4 OT[4] = {{0,0,0,0},{0,0,0,0},{0,0,0,0},{0,0,0,0}};  // O[q=col][d=dt*16+quad*4+r]
  float mrow = -INFINITY;
  float Zp = 0.0f, Zmp = 0.0f;   // per-lane partials over this quad's k subset

  for (int k0 = 0; k0 < Sc; k0 += 64) {
    __syncthreads();  // previous tile fully consumed
    // stage via global_load_lds: wave w covers k-chunks c = w and w+4
#pragma unroll
    for (int jj = 0; jj < 2; jj++) {
      const int c = jj * 4 + w;
      const size_t gk = headoff + (size_t)(k0 + ln) * DHc + c * 8;
      const size_t gv = headoff + (size_t)ln * Sc + k0 + c * 8;
      gl_lds16(khi + gk, &KhiL[c * 512]);
      gl_lds16(klo + gk, &KloL[c * 512]);
      gl_lds16(vt  + gv, &VtL [c * 512]);
    }
    if (t < 64) kmL[t] = Km[b * Sc + k0 + t];
    __syncthreads();

    // ---- S^T: lane gets S[q=col][k = ks*16 + quad*4 + r] ----
    float s[4][4];
#pragma unroll
    for (int ks = 0; ks < 4; ks++) {
      const int base0 = (quad * 64 + ks * 16 + col) * 8;
      const int base1 = ((quad + 4) * 64 + ks * 16 + col) * 8;
      const s16x8 kh0 = *(const s16x8*)&KhiL[base0];
      const s16x8 kh1 = *(const s16x8*)&KhiL[base1];
      const s16x8 kl0 = *(const s16x8*)&KloL[base0];
      const s16x8 kl1 = *(const s16x8*)&KloL[base1];
      f32x4 a = {0,0,0,0};
      a = __builtin_amdgcn_mfma_f32_16x16x32_bf16(kh0, qh0, a, 0, 0, 0);
      a = __builtin_amdgcn_mfma_f32_16x16x32_bf16(kh1, qh1, a, 0, 0, 0);
      a = __builtin_amdgcn_mfma_f32_16x16x32_bf16(kh0, ql0, a, 0, 0, 0);
      a = __builtin_amdgcn_mfma_f32_16x16x32_bf16(kh1, ql1, a, 0, 0, 0);
      a = __builtin_amdgcn_mfma_f32_16x16x32_bf16(kl0, qh0, a, 0, 0, 0);
      a = __builtin_amdgcn_mfma_f32_16x16x32_bf16(kl1, qh1, a, 0, 0, 0);
#pragma unroll
      for (int r = 0; r < 4; r++) s[ks][r] = a[r] * SCALE;
    }

    // ---- online softmax, lane-local over 16 k's + 2 quad swizzles ----
    float tmax = s[0][0];
#pragma unroll
    for (int ks = 0; ks < 4; ks++)
#pragma unroll
      for (int r = 0; r < 4; r++) tmax = fmaxf(tmax, s[ks][r]);
    tmax = fmaxf(tmax, __shfl_xor(tmax, 16, 64));
    tmax = fmaxf(tmax, __shfl_xor(tmax, 32, 64));

    const float mn    = fmaxf(mrow, tmax);
    const float alpha = __expf(mrow - mn);
    mrow = mn;

    float ps = 0.0f, pms = 0.0f;
    const int prow = (w * 16 + col) * LDP;
#pragma unroll
    for (int ks = 0; ks < 4; ks++) {
      const float4 km4 = *(const float4*)&kmL[ks * 16 + quad * 4];
      const float p0 = __expf(s[ks][0] - mn), p1 = __expf(s[ks][1] - mn);
      const float p2 = __expf(s[ks][2] - mn), p3 = __expf(s[ks][3] - mn);
      const float q0 = p0 * km4.x, q1 = p1 * km4.y, q2 = p2 * km4.z, q3 = p3 * km4.w;
      ps  += (p0 + p1) + (p2 + p3);
      pms += (q0 + q1) + (q2 + q3);
      uint2 pv;
      pv.x = pk2bf(q0, q1);
      pv.y = pk2bf(q2, q3);
      *(uint2*)&PmL[prow + ks * 16 + quad * 4] = pv;  // P[q=col][k 4-contig]
    }
    Zp  = Zp  * alpha + ps;
    Zmp = Zmp * alpha + pms;
#pragma unroll
    for (int dt = 0; dt < 4; dt++) OT[dt] *= alpha;   // alpha lane-uniform (per q)

    // ---- O^T += V^T · P^T ----
    const s16x8 p0 = *(const s16x8*)&PmL[prow + quad * 8];        // kk 0..31
    const s16x8 p1 = *(const s16x8*)&PmL[prow + 32 + quad * 8];   // kk 32..63
#pragma unroll
    for (int dt = 0; dt < 4; dt++) {
      const s16x8 a0 = *(const s16x8*)&VtL[(quad * 64 + dt * 16 + col) * 8];
      const s16x8 a1 = *(const s16x8*)&VtL[((quad + 4) * 64 + dt * 16 + col) * 8];
      OT[dt] = __builtin_amdgcn_mfma_f32_16x16x32_bf16(a0, p0, OT[dt], 0, 0, 0);
      OT[dt] = __builtin_amdgcn_mfma_f32_16x16x32_bf16(a1, p1, OT[dt], 0, 0, 0);
    }
  }

  // ---- deferred Z/Zm reduction across quads (each lane: one q-row) ----
  Zp  += __shfl_xor(Zp,  16, 64);  Zp  += __shfl_xor(Zp,  32, 64);
  Zmp += __shfl_xor(Zmp, 16, 64);  Zmp += __shfl_xor(Zmp, 32, 64);

  const int q     = qbase + col;
  const float qmv = Qm[b * Sc + q];
  const float rden = (qmv != 0.0f) ? 1.0f / (Zmp + EPS_TERM * Zp) : 0.0f;

  // ctx bf16 [B,S,HID]; lane writes 4 contiguous d per dt (8B packed)
  ushort* crow = ctx + (size_t)(b * Sc + q) * HIDc + h * DHc + quad * 4;
#pragma unroll
  for (int dt = 0; dt < 4; dt++) {
    uint2 ov;
    ov.x = pk2bf(OT[dt][0] * rden, OT[dt][1] * rden);
    ov.y = pk2bf(OT[dt][2] * rden, OT[dt][3] * rden);
    *(uint2*)(crow + dt * 16) = ov;
  }
}

// ---------------------------------------------------------------------------
extern "C" void kernel_launch(void* const* d_in, const int* in_sizes, int n_in,
                              void* d_out, int out_size, void* d_ws, size_t ws_size,
                              hipStream_t stream)
{
  const float* Q  = (const float*)d_in[0];
  const float* K  = (const float*)d_in[1];
  const float* V  = (const float*)d_in[2];
  const float* Qm = (const float*)d_in[3];
  const float* Km = (const float*)d_in[4];
  const float* Wq = (const float*)d_in[5];
  const float* bq = (const float*)d_in[6];
  const float* Wk = (const float*)d_in[7];
  const float* bk = (const float*)d_in[8];
  const float* Wv = (const float*)d_in[9];
  const float* bv = (const float*)d_in[10];
  const float* Wo = (const float*)d_in[11];
  const float* bo = (const float*)d_in[12];
  float* out = (float*)d_out;

  const size_t NEL = (size_t)Mc * HIDc;   // 8.39M
  const size_t WEL = (size_t)HIDc * HIDc; // 1.05M

  ushort* Wqh = (ushort*)d_ws;
  ushort* Wql = Wqh + WEL;
  ushort* Wkh = Wql + WEL;
  ushort* Wkl = Wkh + WEL;
  ushort* Wvh = Wkl + WEL;
  ushort* Woh = Wvh + WEL;
  ushort* qhi = Woh + WEL;
  ushort* qlo = qhi + NEL;
  ushort* khi = qlo + NEL;
  ushort* klo = khi + NEL;
  ushort* vt  = klo + NEL;
  ushort* A0  = vt  + NEL;   // scratch (input conversions), reused
  ushort* A1  = A0  + NEL;   // scratch; later aliased as bf16 ctx
  // total: 6*WEL + 7*NEL ushorts ~= 130 MB

  const int n4i = (int)(NEL / 4);   // 2097152 -> 8192 blocks
  const int n4w = (int)(WEL / 4);   // 262144  -> 1024 blocks/segment

  // all weight conversions in one launch
  cvt_weights<<<4 * (n4w / 256), 256, 0, stream>>>(
      (const float4*)Wq, (const float4*)Wk, (const float4*)Wv, (const float4*)Wo,
      (ushort4*)Wqh, (ushort4*)Wql, (ushort4*)Wkh, (ushort4*)Wkl,
      (ushort4*)Wvh, (ushort4*)Woh, n4w);

  dim3 gg(HIDc / 128, Mc / 128);   // (8, 64)

  // Q projection (3-pass split, near-fp32)
  cvt_split<<<n4i / 256, 256, 0, stream>>>((const float4*)Q, (ushort4*)A0, (ushort4*)A1, n4i);
  mfma_gemm<true><<<gg, 256, 0, stream>>>(A0, A1, Wqh, Wql, bq, qhi, qlo, 1);

  // K projection
  cvt_split<<<n4i / 256, 256, 0, stream>>>((const float4*)K, (ushort4*)A0, (ushort4*)A1, n4i);
  mfma_gemm<true><<<gg, 256, 0, stream>>>(A0, A1, Wkh, Wkl, bk, khi, klo, 1);

  // V projection (single-pass, transposed head layout)
  cvt_one<<<n4i / 256, 256, 0, stream>>>((const float4*)V, (ushort4*)A0, n4i);
  mfma_gemm<false><<<gg, 256, 0, stream>>>(A0, nullptr, Wvh, nullptr, bv, vt, nullptr, 2);

  // attention -> bf16 ctx (reuses A1)
  attn_mfma<<<Bc * NHc * (Sc / 64), 256, 0, stream>>>(qhi, qlo, khi, klo, vt, Qm, Km, A1);

  // output projection
  mfma_gemm<false><<<gg, 256, 0, stream>>>(A1, nullptr, Woh, nullptr, bo, out, nullptr, 0);
}

// Round 6
// 524.239 us; speedup vs baseline: 15.4701x; 1.0138x over previous
//
#include <hip/hip_runtime.h>
#include <math.h>

// Problem constants
constexpr int Bc   = 8;
constexpr int Sc   = 1024;
constexpr int HIDc = 1024;
constexpr int NHc  = 16;
constexpr int DHc  = 64;
constexpr int Mc   = Bc * Sc;                 // 8192 rows for all GEMMs
constexpr int Kc2  = 1024;                    // K dim for all GEMMs
constexpr float SCALE    = 8.0f;              // ref divides by DH**-0.5 == *sqrt(64)
constexpr float EPS_TERM = 1024.0f * 1e-8f;   // S * ZERO in the renorm denominator

typedef short s16x8 __attribute__((ext_vector_type(8)));   // 8 bf16 (4 VGPRs)
typedef float f32x4 __attribute__((ext_vector_type(4)));

__device__ __forceinline__ ushort f2bf(float f) {          // RNE float->bf16 bits
  unsigned u = __float_as_uint(f);
  u += 0x7FFFu + ((u >> 16) & 1u);
  return (ushort)(u >> 16);
}
__device__ __forceinline__ float bf2f(ushort h) {
  return __uint_as_float(((unsigned)h) << 16);
}
__device__ __forceinline__ unsigned pk2bf(float a, float b) {  // pack 2 bf16
  return (unsigned)f2bf(a) | ((unsigned)f2bf(b) << 16);
}

// async global->LDS, 16B per lane; LDS dest = wave-uniform base + lane*16
__device__ __forceinline__ void gl_lds16(const ushort* g, ushort* l) {
  __builtin_amdgcn_global_load_lds(
      (const __attribute__((address_space(1))) void*)g,
      (__attribute__((address_space(3))) void*)l, 16, 0, 0);
}

// split 8 fp32 -> bf16 hi8 + lo8 (RNE; identical numerics to cvt_split)
__device__ __forceinline__ void split8(const float4 v0, const float4 v1,
                                       s16x8& hi, s16x8& lo) {
  const float f[8] = {v0.x, v0.y, v0.z, v0.w, v1.x, v1.y, v1.z, v1.w};
  ushort h[8], l[8];
#pragma unroll
  for (int i = 0; i < 8; i++) {
    h[i] = f2bf(f[i]);
    l[i] = f2bf(f[i] - bf2f(h[i]));
  }
#pragma unroll
  for (int i = 0; i < 8; i++) { hi[i] = (short)h[i]; lo[i] = (short)l[i]; }
}

// ---------------------------------------------------------------------------
// Weight conversions (one launch): seg 0=Wq(split) 1=Wk(split) 2=Wv 3=Wo
// ---------------------------------------------------------------------------
__global__ __launch_bounds__(256) void cvt_weights(
    const float4* __restrict__ Wq, const float4* __restrict__ Wk,
    const float4* __restrict__ Wv, const float4* __restrict__ Wo,
    ushort4* __restrict__ Wqh, ushort4* __restrict__ Wql,
    ushort4* __restrict__ Wkh, ushort4* __restrict__ Wkl,
    ushort4* __restrict__ Wvh, ushort4* __restrict__ Woh, int n4w)
{
  const int bpseg = n4w / 256;                 // blocks per segment (1024)
  const int seg   = blockIdx.x / bpseg;
  const int li    = (blockIdx.x - seg * bpseg) * 256 + threadIdx.x;
  if (li >= n4w) return;
  if (seg == 0) {
    const float4 v = Wq[li];
    ushort4 h, l;
    h.x = f2bf(v.x); l.x = f2bf(v.x - bf2f(h.x));
    h.y = f2bf(v.y); l.y = f2bf(v.y - bf2f(h.y));
    h.z = f2bf(v.z); l.z = f2bf(v.z - bf2f(h.z));
    h.w = f2bf(v.w); l.w = f2bf(v.w - bf2f(h.w));
    Wqh[li] = h; Wql[li] = l;
  } else if (seg == 1) {
    const float4 v = Wk[li];
    ushort4 h, l;
    h.x = f2bf(v.x); l.x = f2bf(v.x - bf2f(h.x));
    h.y = f2bf(v.y); l.y = f2bf(v.y - bf2f(h.y));
    h.z = f2bf(v.z); l.z = f2bf(v.z - bf2f(h.z));
    h.w = f2bf(v.w); l.w = f2bf(v.w - bf2f(h.w));
    Wkh[li] = h; Wkl[li] = l;
  } else {
    const float4 v = (seg == 2) ? Wv[li] : Wo[li];
    ushort4 h;
    h.x = f2bf(v.x); h.y = f2bf(v.y); h.z = f2bf(v.z); h.w = f2bf(v.w);
    if (seg == 2) Wvh[li] = h; else Woh[li] = h;
  }
}

// ---------------------------------------------------------------------------
// Fused QKV projection GEMM (one launch, blockIdx.z = 0:Q 1:K 2:V).
// C[m][n] = sum_k A[m][k]*W[n][k] + bias[n], A fp32 (d_in), W bf16 (pre-cvt).
// z<2: A split to hi/lo in-register during staging; 3-term MFMA (near-fp32);
//      output bf16 hi/lo pair in head layout [B,NH,S,DH].
// z=2: single bf16 pass; output bf16 transposed head layout [B,NH,DH,S].
// 128x128 tile, 4 waves 2x2 of 64x64, BK=32, chunk-major LDS.
// ---------------------------------------------------------------------------
__global__ __launch_bounds__(256, 3) void qkv_gemm(
    const float* __restrict__ Qf, const float* __restrict__ Kf,
    const float* __restrict__ Vf,
    const ushort* __restrict__ Wqh, const ushort* __restrict__ Wql,
    const ushort* __restrict__ Wkh, const ushort* __restrict__ Wkl,
    const ushort* __restrict__ Wvh,
    const float* __restrict__ bq, const float* __restrict__ bk,
    const float* __restrict__ bv,
    ushort* __restrict__ qhi, ushort* __restrict__ qlo,
    ushort* __restrict__ khi, ushort* __restrict__ klo,
    ushort* __restrict__ vt)
{
  __shared__ ushort AhL[4096];
  __shared__ ushort BhL[4096];
  __shared__ ushort AlL[4096];
  __shared__ ushort BlL[4096];

  const int z = blockIdx.z;
  const bool split = (z < 2);
  const float*  Af = (z == 0) ? Qf : (z == 1) ? Kf : Vf;
  const ushort* Bh = (z == 0) ? Wqh : (z == 1) ? Wkh : Wvh;
  const ushort* Bl = (z == 0) ? Wql : Wkl;   // unused when z==2
  const float* bias = (z == 0) ? bq : (z == 1) ? bk : bv;

  const int t    = threadIdx.x;
  const int w    = t >> 6;
  const int ln   = t & 63;
  const int col  = ln & 15;
  const int quad = ln >> 4;
  const int wm   = w >> 1, wn = w & 1;
  const int m0   = blockIdx.y * 128;
  const int n0   = blockIdx.x * 128;

  f32x4 acc[4][4] = {};

  const int sA = w * 128;  // this wave's 128-chunk staging range

  for (int k0 = 0; k0 < Kc2; k0 += 32) {
    // A fp32 loads to VGPRs BEFORE the barrier (prefetch over prev tile's MFMA)
    float4 av[2][2];
#pragma unroll
    for (int j = 0; j < 2; j++) {
      const int s = sA + j * 64 + ln;
      const int r = s & 127, c = s >> 7;
      const float4* ga = (const float4*)(Af + (size_t)(m0 + r) * Kc2 + k0 + c * 8);
      av[j][0] = ga[0];
      av[j][1] = ga[1];
    }

    __syncthreads();  // previous tile consumed

    // B (weights) via async global->LDS
#pragma unroll
    for (int j = 0; j < 2; j++) {
      const int s = sA + j * 64 + ln;
      const int r = s & 127, c = s >> 7;
      const size_t goB = (size_t)(n0 + r) * Kc2 + k0 + c * 8;
      gl_lds16(Bh + goB, &BhL[(size_t)(sA + j * 64) * 8]);
      if (split) gl_lds16(Bl + goB, &BlL[(size_t)(sA + j * 64) * 8]);
    }
    // A: split in registers, write chunk-major
#pragma unroll
    for (int j = 0; j < 2; j++) {
      const int s = sA + j * 64 + ln;
      s16x8 hi, lo;
      split8(av[j][0], av[j][1], hi, lo);
      *(s16x8*)&AhL[(size_t)s * 8] = hi;
      if (split) *(s16x8*)&AlL[(size_t)s * 8] = lo;
    }
    __syncthreads();  // drains lgkm (A writes) + vm (B gl_lds)

    s16x8 a_h[4], b_h[4], a_l[4], b_l[4];
#pragma unroll
    for (int i = 0; i < 4; i++) {
      const int ai = (quad * 128 + wm * 64 + i * 16 + col) * 8;
      const int bi = (quad * 128 + wn * 64 + i * 16 + col) * 8;
      a_h[i] = *(const s16x8*)&AhL[ai];
      b_h[i] = *(const s16x8*)&BhL[bi];
      if (split) {
        a_l[i] = *(const s16x8*)&AlL[ai];
        b_l[i] = *(const s16x8*)&BlL[bi];
      }
    }
#pragma unroll
    for (int i = 0; i < 4; i++)
#pragma unroll
      for (int jj = 0; jj < 4; jj++) {
        acc[i][jj] = __builtin_amdgcn_mfma_f32_16x16x32_bf16(a_h[i], b_h[jj], acc[i][jj], 0, 0, 0);
        if (split) {
          acc[i][jj] = __builtin_amdgcn_mfma_f32_16x16x32_bf16(a_h[i], b_l[jj], acc[i][jj], 0, 0, 0);
          acc[i][jj] = __builtin_amdgcn_mfma_f32_16x16x32_bf16(a_l[i], b_h[jj], acc[i][jj], 0, 0, 0);
        }
      }
  }

  // epilogue: C/D frag mapping col=lane&15, row=quad*4+reg
  const int mb = m0 + wm * 64;
  const int nb = n0 + wn * 64;
  ushort* Ch = (z == 0) ? qhi : khi;
  ushort* Cl = (z == 0) ? qlo : klo;
#pragma unroll
  for (int i = 0; i < 4; i++)
#pragma unroll
    for (int jj = 0; jj < 4; jj++) {
      const int n  = nb + jj * 16 + col;
      const float bvv = bias[n];
#pragma unroll
      for (int r = 0; r < 4; r++) {
        const int m   = mb + i * 16 + quad * 4 + r;
        const float v = acc[i][jj][r] + bvv;
        const int b_ = m >> 10, s = m & (Sc - 1);
        const int h_ = n >> 6,  d = n & (DHc - 1);
        if (split) {
          const size_t off = (((size_t)b_ * NHc + h_) * Sc + s) * DHc + d;
          const ushort hb = f2bf(v);
          Ch[off] = hb;
          Cl[off] = f2bf(v - bf2f(hb));
        } else {  // transposed V
          const size_t off = (((size_t)b_ * NHc + h_) * DHc + d) * Sc + s;
          vt[off] = f2bf(v);
        }
      }
    }
}

// ---------------------------------------------------------------------------
// Output GEMM: out[m][n] = sum_k ctx[m][k]*Wo[n][k] + bo[n], ctx bf16, out fp32
// ---------------------------------------------------------------------------
__global__ __launch_bounds__(256, 3) void o_gemm(
    const ushort* __restrict__ Ag, const ushort* __restrict__ Bg,
    const float* __restrict__ bias, float* __restrict__ C)
{
  __shared__ ushort AhL[4096];
  __shared__ ushort BhL[4096];

  const int t    = threadIdx.x;
  const int w    = t >> 6;
  const int ln   = t & 63;
  const int col  = ln & 15;
  const int quad = ln >> 4;
  const int wm   = w >> 1, wn = w & 1;
  const int m0   = blockIdx.y * 128;
  const int n0   = blockIdx.x * 128;

  f32x4 acc[4][4] = {};
  const int sA = w * 128;

  for (int k0 = 0; k0 < Kc2; k0 += 32) {
    __syncthreads();
#pragma unroll
    for (int j = 0; j < 2; j++) {
      const int s = sA + j * 64 + ln;
      const int r = s & 127, c = s >> 7;
      gl_lds16(Ag + (size_t)(m0 + r) * Kc2 + k0 + c * 8, &AhL[(size_t)(sA + j * 64) * 8]);
      gl_lds16(Bg + (size_t)(n0 + r) * Kc2 + k0 + c * 8, &BhL[(size_t)(sA + j * 64) * 8]);
    }
    __syncthreads();

    s16x8 a_h[4], b_h[4];
#pragma unroll
    for (int i = 0; i < 4; i++) {
      a_h[i] = *(const s16x8*)&AhL[(quad * 128 + wm * 64 + i * 16 + col) * 8];
      b_h[i] = *(const s16x8*)&BhL[(quad * 128 + wn * 64 + i * 16 + col) * 8];
    }
#pragma unroll
    for (int i = 0; i < 4; i++)
#pragma unroll
      for (int jj = 0; jj < 4; jj++)
        acc[i][jj] = __builtin_amdgcn_mfma_f32_16x16x32_bf16(a_h[i], b_h[jj], acc[i][jj], 0, 0, 0);
  }

  const int mb = m0 + wm * 64;
  const int nb = n0 + wn * 64;
#pragma unroll
  for (int i = 0; i < 4; i++)
#pragma unroll
    for (int jj = 0; jj < 4; jj++) {
      const int n  = nb + jj * 16 + col;
      const float bvv = bias[n];
#pragma unroll
      for (int r = 0; r < 4; r++) {
        const int m = mb + i * 16 + quad * 4 + r;
        C[(size_t)m * HIDc + n] = acc[i][jj][r] + bvv;
      }
    }
}

// ---------------------------------------------------------------------------
// MFMA flash attention, S^T orientation (unchanged from R5).
// ---------------------------------------------------------------------------
constexpr int LDP = 72;   // P LDS row stride (ushorts)

__global__ __launch_bounds__(256, 4) void attn_mfma(
    const ushort* __restrict__ qhi, const ushort* __restrict__ qlo,
    const ushort* __restrict__ khi, const ushort* __restrict__ klo,
    const ushort* __restrict__ vt,  const float* __restrict__ Qm,
    const float* __restrict__ Km,   ushort* __restrict__ ctx)
{
  __shared__ ushort KhiL[4096];     // chunk c*64+r = Khi[r][c*8..+8]
  __shared__ ushort KloL[4096];
  __shared__ ushort VtL [4096];     // chunk c*64+d = V^T[d][c*8..+8]
  __shared__ ushort PmL [64 * LDP];
  __shared__ float  kmL[64];

  const int t    = threadIdx.x;
  const int w    = t >> 6;
  const int ln   = t & 63;
  const int col  = ln & 15;
  const int quad = ln >> 4;

  // XCD-aware remap: 16 whole heads per XCD, q-tiles of a head on one XCD.
  const int id  = blockIdx.x;          // 0..2047
  const int xcd = id & 7;
  const int j   = id >> 3;             // 0..255
  const int bh  = xcd * 16 + (j >> 4);
  const int qt  = j & 15;
  const int b   = bh >> 4;
  const int h   = bh & 15;

  const int qbase = qt * 64 + w * 16;
  const size_t headoff = (size_t)bh * Sc * DHc;

  s16x8 qh0, qh1, ql0, ql1;
  {
    const size_t ro = headoff + (size_t)(qbase + col) * DHc + quad * 8;
    qh0 = *(const s16x8*)(qhi + ro);
    qh1 = *(const s16x8*)(qhi + ro + 32);
    ql0 = *(const s16x8*)(qlo + ro);
    ql1 = *(const s16x8*)(qlo + ro + 32);
  }

  f32x4 OT[4] = {{0,0,0,0},{0,0,0,0},{0,0,0,0},{0,0,0,0}};
  float mrow = -INFINITY;
  float Zp = 0.0f, Zmp = 0.0f;

  for (int k0 = 0; k0 < Sc; k0 += 64) {
    __syncthreads();
#pragma unroll
    for (int jj = 0; jj < 2; jj++) {
      const int c = jj * 4 + w;
      const size_t gk = headoff + (size_t)(k0 + ln) * DHc + c * 8;
      const size_t gv = headoff + (size_t)ln * Sc + k0 + c * 8;
      gl_lds16(khi + gk, &KhiL[c * 512]);
      gl_lds16(klo + gk, &KloL[c * 512]);
      gl_lds16(vt  + gv, &VtL [c * 512]);
    }
    if (t < 64) kmL[t] = Km[b * Sc + k0 + t];
    __syncthreads();

    float s[4][4];
#pragma unroll
    for (int ks = 0; ks < 4; ks++) {
      const int base0 = (quad * 64 + ks * 16 + col) * 8;
      const int base1 = ((quad + 4) * 64 + ks * 16 + col) * 8;
      const s16x8 kh0 = *(const s16x8*)&KhiL[base0];
      const s16x8 kh1 = *(const s16x8*)&KhiL[base1];
      const s16x8 kl0 = *(const s16x8*)&KloL[base0];
      const s16x8 kl1 = *(const s16x8*)&KloL[base1];
      f32x4 a = {0,0,0,0};
      a = __builtin_amdgcn_mfma_f32_16x16x32_bf16(kh0, qh0, a, 0, 0, 0);
      a = __builtin_amdgcn_mfma_f32_16x16x32_bf16(kh1, qh1, a, 0, 0, 0);
      a = __builtin_amdgcn_mfma_f32_16x16x32_bf16(kh0, ql0, a, 0, 0, 0);
      a = __builtin_amdgcn_mfma_f32_16x16x32_bf16(kh1, ql1, a, 0, 0, 0);
      a = __builtin_amdgcn_mfma_f32_16x16x32_bf16(kl0, qh0, a, 0, 0, 0);
      a = __builtin_amdgcn_mfma_f32_16x16x32_bf16(kl1, qh1, a, 0, 0, 0);
#pragma unroll
      for (int r = 0; r < 4; r++) s[ks][r] = a[r] * SCALE;
    }

    float tmax = s[0][0];
#pragma unroll
    for (int ks = 0; ks < 4; ks++)
#pragma unroll
      for (int r = 0; r < 4; r++) tmax = fmaxf(tmax, s[ks][r]);
    tmax = fmaxf(tmax, __shfl_xor(tmax, 16, 64));
    tmax = fmaxf(tmax, __shfl_xor(tmax, 32, 64));

    const float mn    = fmaxf(mrow, tmax);
    const float alpha = __expf(mrow - mn);
    mrow = mn;

    float ps = 0.0f, pms = 0.0f;
    const int prow = (w * 16 + col) * LDP;
#pragma unroll
    for (int ks = 0; ks < 4; ks++) {
      const float4 km4 = *(const float4*)&kmL[ks * 16 + quad * 4];
      const float p0 = __expf(s[ks][0] - mn), p1 = __expf(s[ks][1] - mn);
      const float p2 = __expf(s[ks][2] - mn), p3 = __expf(s[ks][3] - mn);
      const float q0 = p0 * km4.x, q1 = p1 * km4.y, q2 = p2 * km4.z, q3 = p3 * km4.w;
      ps  += (p0 + p1) + (p2 + p3);
      pms += (q0 + q1) + (q2 + q3);
      uint2 pv;
      pv.x = pk2bf(q0, q1);
      pv.y = pk2bf(q2, q3);
      *(uint2*)&PmL[prow + ks * 16 + quad * 4] = pv;
    }
    Zp  = Zp  * alpha + ps;
    Zmp = Zmp * alpha + pms;
#pragma unroll
    for (int dt = 0; dt < 4; dt++) OT[dt] *= alpha;

    const s16x8 p0 = *(const s16x8*)&PmL[prow + quad * 8];
    const s16x8 p1 = *(const s16x8*)&PmL[prow + 32 + quad * 8];
#pragma unroll
    for (int dt = 0; dt < 4; dt++) {
      const s16x8 a0 = *(const s16x8*)&VtL[(quad * 64 + dt * 16 + col) * 8];
      const s16x8 a1 = *(const s16x8*)&VtL[((quad + 4) * 64 + dt * 16 + col) * 8];
      OT[dt] = __builtin_amdgcn_mfma_f32_16x16x32_bf16(a0, p0, OT[dt], 0, 0, 0);
      OT[dt] = __builtin_amdgcn_mfma_f32_16x16x32_bf16(a1, p1, OT[dt], 0, 0, 0);
    }
  }

  Zp  += __shfl_xor(Zp,  16, 64);  Zp  += __shfl_xor(Zp,  32, 64);
  Zmp += __shfl_xor(Zmp, 16, 64);  Zmp += __shfl_xor(Zmp, 32, 64);

  const int q     = qbase + col;
  const float qmv = Qm[b * Sc + q];
  const float rden = (qmv != 0.0f) ? 1.0f / (Zmp + EPS_TERM * Zp) : 0.0f;

  ushort* crow = ctx + (size_t)(b * Sc + q) * HIDc + h * DHc + quad * 4;
#pragma unroll
  for (int dt = 0; dt < 4; dt++) {
    uint2 ov;
    ov.x = pk2bf(OT[dt][0] * rden, OT[dt][1] * rden);
    ov.y = pk2bf(OT[dt][2] * rden, OT[dt][3] * rden);
    *(uint2*)(crow + dt * 16) = ov;
  }
}

// ---------------------------------------------------------------------------
extern "C" void kernel_launch(void* const* d_in, const int* in_sizes, int n_in,
                              void* d_out, int out_size, void* d_ws, size_t ws_size,
                              hipStream_t stream)
{
  const float* Q  = (const float*)d_in[0];
  const float* K  = (const float*)d_in[1];
  const float* V  = (const float*)d_in[2];
  const float* Qm = (const float*)d_in[3];
  const float* Km = (const float*)d_in[4];
  const float* Wq = (const float*)d_in[5];
  const float* bq = (const float*)d_in[6];
  const float* Wk = (const float*)d_in[7];
  const float* bk = (const float*)d_in[8];
  const float* Wv = (const float*)d_in[9];
  const float* bv = (const float*)d_in[10];
  const float* Wo = (const float*)d_in[11];
  const float* bo = (const float*)d_in[12];
  float* out = (float*)d_out;

  const size_t NEL = (size_t)Mc * HIDc;   // 8.39M
  const size_t WEL = (size_t)HIDc * HIDc; // 1.05M

  ushort* Wqh = (ushort*)d_ws;
  ushort* Wql = Wqh + WEL;
  ushort* Wkh = Wql + WEL;
  ushort* Wkl = Wkh + WEL;
  ushort* Wvh = Wkl + WEL;
  ushort* Woh = Wvh + WEL;
  ushort* qhi = Woh + WEL;
  ushort* qlo = qhi + NEL;
  ushort* khi = qlo + NEL;
  ushort* klo = khi + NEL;
  ushort* vt  = klo + NEL;
  ushort* ctx = vt  + NEL;
  // total: 6*WEL + 6*NEL ushorts ~= 113 MB

  const int n4w = (int)(WEL / 4);   // 262144 -> 1024 blocks/segment

  cvt_weights<<<4 * (n4w / 256), 256, 0, stream>>>(
      (const float4*)Wq, (const float4*)Wk, (const float4*)Wv, (const float4*)Wo,
      (ushort4*)Wqh, (ushort4*)Wql, (ushort4*)Wkh, (ushort4*)Wkl,
      (ushort4*)Wvh, (ushort4*)Woh, n4w);

  // fused QKV projections (conversion folded into staging)
  dim3 gqkv(HIDc / 128, Mc / 128, 3);   // (8, 64, 3)
  qkv_gemm<<<gqkv, 256, 0, stream>>>(Q, K, V,
      Wqh, Wql, Wkh, Wkl, Wvh, bq, bk, bv, qhi, qlo, khi, klo, vt);

  // attention -> bf16 ctx
  attn_mfma<<<Bc * NHc * (Sc / 64), 256, 0, stream>>>(qhi, qlo, khi, klo, vt, Qm, Km, ctx);

  // output projection
  dim3 gg(HIDc / 128, Mc / 128);        // (8, 64)
  o_gemm<<<gg, 256, 0, stream>>>(ctx, Woh, bo, out);
}